// Round 1
// baseline (762.461 us; speedup 1.0000x reference)
//
#include <hip/hip_runtime.h>
#include <hip/hip_bf16.h>
#include <cstdint>
#include <cstddef>

// Problem: B=128, S=512, H=512, D=1024
// Outputs (flat in d_out): context (128*1024) | aw (128*512) | new_coverage (128*512)

typedef __attribute__((ext_vector_type(8))) short bf16x8;
typedef __attribute__((ext_vector_type(4))) float f32x4;

__device__ __forceinline__ short f2bf(float f) {
    union { float f; uint32_t u; } v; v.f = f;
    uint32_t u = v.u + 0x7fffu + ((v.u >> 16) & 1u);  // RNE
    return (short)(u >> 16);
}

__device__ __forceinline__ bf16x8 cvt8(float4 a, float4 b) {
    bf16x8 r;
    r[0] = f2bf(a.x); r[1] = f2bf(a.y); r[2] = f2bf(a.z); r[3] = f2bf(a.w);
    r[4] = f2bf(b.x); r[5] = f2bf(b.y); r[6] = f2bf(b.z); r[7] = f2bf(b.w);
    return r;
}

__device__ __forceinline__ float fast_tanh(float x) {
    x = fminf(10.f, fmaxf(-10.f, x));
    float e = __expf(2.f * x);
    return (e - 1.f) / (e + 1.f);
}

// ---------------- fp32 -> bf16 conversion (for weight matrices) ----------------
__global__ void cvt_f32_bf16(const float* __restrict__ src, short* __restrict__ dst, int n) {
    int i = (blockIdx.x * 256 + threadIdx.x) * 4;
    if (i < n) {
        float4 f = *(const float4*)(src + i);
        short4 o;
        o.x = f2bf(f.x); o.y = f2bf(f.y); o.z = f2bf(f.z); o.w = f2bf(f.w);
        *(short4*)(dst + i) = o;
    }
}

// ---------------- dec_feat = s_t @ Ws^T + Ws_b  (M=128, N=1024, K=1024) --------
// s_t[b,k] = k<512 ? h_dec[b,k] : c_dec[b,k-512]
__global__ __launch_bounds__(256) void dec_gemm(
    const float* __restrict__ hd, const float* __restrict__ cd,
    const short* __restrict__ Ws, const float* __restrict__ Wsb,
    float* __restrict__ dec_feat)
{
    __shared__ __align__(16) short As[128 * 40];
    __shared__ __align__(16) short Bs[128 * 40];
    const int t = threadIdx.x;
    const int bx = blockIdx.x;                 // n-tile 0..7
    const int wv = t >> 6, lane = t & 63, q = lane >> 4, c = lane & 15;
    const int wm = wv & 1, wn = wv >> 1;
    const int ar = t >> 1, ah = t & 1;

    const short* bptr = Ws + ((size_t)(bx * 128 + ar)) * 1024 + ah * 16;
    short* awr = &As[ar * 40 + ah * 16];
    short* bwr = &Bs[ar * 40 + ah * 16];

    f32x4 acc[4][4];
#pragma unroll
    for (int i = 0; i < 4; ++i)
#pragma unroll
        for (int j = 0; j < 4; ++j) acc[i][j] = (f32x4){0.f, 0.f, 0.f, 0.f};

    for (int k0 = 0; k0 < 1024; k0 += 32) {
        const int k = k0 + ah * 16;
        const float* src = (k < 512) ? (hd + (size_t)ar * 512 + k)
                                     : (cd + (size_t)ar * 512 + (k - 512));
        const float4* ap = (const float4*)src;
        float4 a0 = ap[0], a1 = ap[1], a2 = ap[2], a3 = ap[3];
        bf16x8 bv0 = *(const bf16x8*)(bptr + k0);
        bf16x8 bv1 = *(const bf16x8*)(bptr + k0 + 8);
        *(bf16x8*)awr = cvt8(a0, a1);
        *(bf16x8*)(awr + 8) = cvt8(a2, a3);
        *(bf16x8*)bwr = bv0;
        *(bf16x8*)(bwr + 8) = bv1;
        __syncthreads();
        bf16x8 af[4], bf[4];
#pragma unroll
        for (int i = 0; i < 4; ++i) af[i] = *(const bf16x8*)&As[(wm * 64 + i * 16 + c) * 40 + q * 8];
#pragma unroll
        for (int j = 0; j < 4; ++j) bf[j] = *(const bf16x8*)&Bs[(wn * 64 + j * 16 + c) * 40 + q * 8];
#pragma unroll
        for (int i = 0; i < 4; ++i)
#pragma unroll
            for (int j = 0; j < 4; ++j)
                acc[i][j] = __builtin_amdgcn_mfma_f32_16x16x32_bf16(af[i], bf[j], acc[i][j], 0, 0, 0);
        __syncthreads();
    }

    const int n0 = bx * 128 + wn * 64;
    float wsb_e[4];
#pragma unroll
    for (int j = 0; j < 4; ++j) wsb_e[j] = Wsb[n0 + j * 16 + c];
#pragma unroll
    for (int i = 0; i < 4; ++i)
#pragma unroll
        for (int rr = 0; rr < 4; ++rr) {
            int bidx = wm * 64 + i * 16 + q * 4 + rr;  // b index (M row)
#pragma unroll
            for (int j = 0; j < 4; ++j) {
                int e = n0 + j * 16 + c;
                dec_feat[(size_t)bidx * 1024 + e] = acc[i][j][rr] + wsb_e[j];
            }
        }
}

// ---------------- main: score[b,s] += sum_e v[e]*tanh(encWh + dec + cov*wc) ----
// M = B*S = 65536 (rows of enc), N = 1024 (e), K = 1024 (d)
__global__ __launch_bounds__(256) void attn_score_gemm(
    const float* __restrict__ enc, const short* __restrict__ Wh,
    const float* __restrict__ dec_feat, const float* __restrict__ cov,
    const float* __restrict__ wc_w, const float* __restrict__ v_w,
    float* __restrict__ score)
{
    __shared__ __align__(16) short As[128 * 40];
    __shared__ __align__(16) short Bs[128 * 40];
    const int t = threadIdx.x;
    const int bx = blockIdx.x;                 // n-tile 0..7 (fast: shares A-tile)
    const int by = blockIdx.y;                 // m-tile 0..511
    const int b  = by >> 2;                    // 4 m-tiles per batch row
    const int s0 = (by & 3) * 128;

    const int wv = t >> 6, lane = t & 63, q = lane >> 4, c = lane & 15;
    const int wm = wv & 1, wn = wv >> 1;
    const int ar = t >> 1, ah = t & 1;

    const float* aptr = enc + ((size_t)(by * 128 + ar)) * 1024 + ah * 16;
    const short* bptr = Wh + ((size_t)(bx * 128 + ar)) * 1024 + ah * 16;
    short* awr = &As[ar * 40 + ah * 16];
    short* bwr = &Bs[ar * 40 + ah * 16];

    f32x4 acc[4][4];
#pragma unroll
    for (int i = 0; i < 4; ++i)
#pragma unroll
        for (int j = 0; j < 4; ++j) acc[i][j] = (f32x4){0.f, 0.f, 0.f, 0.f};

    for (int k0 = 0; k0 < 1024; k0 += 32) {
        const float4* ap = (const float4*)(aptr + k0);
        float4 a0 = ap[0], a1 = ap[1], a2 = ap[2], a3 = ap[3];
        bf16x8 bv0 = *(const bf16x8*)(bptr + k0);
        bf16x8 bv1 = *(const bf16x8*)(bptr + k0 + 8);
        *(bf16x8*)awr = cvt8(a0, a1);
        *(bf16x8*)(awr + 8) = cvt8(a2, a3);
        *(bf16x8*)bwr = bv0;
        *(bf16x8*)(bwr + 8) = bv1;
        __syncthreads();
        bf16x8 af[4], bf[4];
#pragma unroll
        for (int i = 0; i < 4; ++i) af[i] = *(const bf16x8*)&As[(wm * 64 + i * 16 + c) * 40 + q * 8];
#pragma unroll
        for (int j = 0; j < 4; ++j) bf[j] = *(const bf16x8*)&Bs[(wn * 64 + j * 16 + c) * 40 + q * 8];
#pragma unroll
        for (int i = 0; i < 4; ++i)
#pragma unroll
            for (int j = 0; j < 4; ++j)
                acc[i][j] = __builtin_amdgcn_mfma_f32_16x16x32_bf16(af[i], bf[j], acc[i][j], 0, 0, 0);
        __syncthreads();
    }

    // Epilogue: att = acc + dec_feat[b,e] + cov[b,s]*wc[e]; p = sum_e v[e]*tanh(att)
    const int n0 = bx * 128 + wn * 64;
    float v_e[4], wc_e[4], dec_e[4];
#pragma unroll
    for (int j = 0; j < 4; ++j) {
        int e = n0 + j * 16 + c;
        v_e[j]  = v_w[e];
        wc_e[j] = wc_w[e];
        dec_e[j] = dec_feat[(size_t)b * 1024 + e];
    }
    const float* covb = cov + (size_t)b * 512;
    float* scb = score + (size_t)b * 512;
#pragma unroll
    for (int i = 0; i < 4; ++i)
#pragma unroll
        for (int rr = 0; rr < 4; ++rr) {
            int m_local = wm * 64 + i * 16 + q * 4 + rr;
            int s = s0 + m_local;
            float cs = covb[s];
            float p = 0.f;
#pragma unroll
            for (int j = 0; j < 4; ++j) {
                float att = acc[i][j][rr] + dec_e[j] + cs * wc_e[j];
                p += v_e[j] * fast_tanh(att);
            }
            p += __shfl_xor(p, 1);
            p += __shfl_xor(p, 2);
            p += __shfl_xor(p, 4);
            p += __shfl_xor(p, 8);
            if (c == 0) atomicAdd(&scb[s], p);
        }
}

// ---------------- softmax over S with mask + renormalize -----------------------
__global__ __launch_bounds__(512) void softmax_kernel(
    const float* __restrict__ score, const float* __restrict__ mask,
    const float* __restrict__ cov, float* __restrict__ aw, float* __restrict__ ncov)
{
    __shared__ float red[8];
    const int b = blockIdx.x, t = threadIdx.x;
    const int w = t >> 6, lane = t & 63;
    const size_t idx = (size_t)b * 512 + t;
    float sc = score[idx];

    float m = sc;
#pragma unroll
    for (int o = 1; o < 64; o <<= 1) m = fmaxf(m, __shfl_xor(m, o));
    if (lane == 0) red[w] = m;
    __syncthreads();
#pragma unroll
    for (int i = 0; i < 8; ++i) m = fmaxf(m, red[i]);
    __syncthreads();

    float e = __expf(sc - m);
    float s = e;
#pragma unroll
    for (int o = 1; o < 64; o <<= 1) s += __shfl_xor(s, o);
    if (lane == 0) red[w] = s;
    __syncthreads();
    s = 0.f;
#pragma unroll
    for (int i = 0; i < 8; ++i) s += red[i];
    __syncthreads();

    float wv = (e / s) * mask[idx];
    float s2 = wv;
#pragma unroll
    for (int o = 1; o < 64; o <<= 1) s2 += __shfl_xor(s2, o);
    if (lane == 0) red[w] = s2;
    __syncthreads();
    s2 = 0.f;
#pragma unroll
    for (int i = 0; i < 8; ++i) s2 += red[i];

    float awv = wv / s2;
    aw[idx] = awv;
    ncov[idx] = cov[idx] + awv;
}

// ---------------- context[b,d] = sum_s aw[b,s] * enc[b,s,d] --------------------
__global__ __launch_bounds__(256) void context_kernel(
    const float* __restrict__ enc, const float* __restrict__ aw, float* __restrict__ ctx)
{
    const int schunk = blockIdx.x;  // 0..3
    const int b = blockIdx.y;       // 0..127
    const int t = threadIdx.x;      // 256 threads x 4 floats = 1024 = D
    const float* ebase = enc + ((size_t)b * 512 + schunk * 128) * 1024 + t * 4;
    const float* awp = aw + (size_t)b * 512 + schunk * 128;
    float ax = 0.f, ay = 0.f, az = 0.f, aww = 0.f;
#pragma unroll 4
    for (int s = 0; s < 128; ++s) {
        float w = awp[s];
        float4 e4 = *(const float4*)(ebase + (size_t)s * 1024);
        ax += w * e4.x; ay += w * e4.y; az += w * e4.z; aww += w * e4.w;
    }
    float* cp = ctx + (size_t)b * 1024 + t * 4;
    atomicAdd(cp + 0, ax);
    atomicAdd(cp + 1, ay);
    atomicAdd(cp + 2, az);
    atomicAdd(cp + 3, aww);
}

extern "C" void kernel_launch(void* const* d_in, const int* in_sizes, int n_in,
                              void* d_out, int out_size, void* d_ws, size_t ws_size,
                              hipStream_t stream) {
    const float* hd   = (const float*)d_in[0];  // (1,128,512)
    const float* cd   = (const float*)d_in[1];  // (1,128,512)
    const float* enc  = (const float*)d_in[2];  // (128,512,1024)
    const float* mask = (const float*)d_in[3];  // (128,512)
    const float* cov  = (const float*)d_in[4];  // (128,512)
    const float* Wh   = (const float*)d_in[5];  // (1024,1024)
    const float* Ws   = (const float*)d_in[6];  // (1024,1024)
    const float* Wsb  = (const float*)d_in[7];  // (1024,)
    const float* vw   = (const float*)d_in[8];  // (1024,)
    const float* wcw  = (const float*)d_in[9];  // (1024,)

    float* out  = (float*)d_out;
    float* ctx  = out;                 // 131072
    float* aw   = out + 131072;        // 65536
    float* ncov = out + 196608;        // 65536

    char* ws = (char*)d_ws;
    float* score    = (float*)ws;                              // 256 KB
    float* dec_feat = (float*)(ws + (256 << 10));              // 512 KB
    short* Wh_bf    = (short*)(ws + (768 << 10));              // 2 MB
    short* Ws_bf    = (short*)(ws + (768 << 10) + (2048 << 10)); // 2 MB

    hipMemsetAsync(score, 0, 128 * 512 * sizeof(float), stream);
    hipMemsetAsync(ctx, 0, 128 * 1024 * sizeof(float), stream);

    cvt_f32_bf16<<<1024, 256, 0, stream>>>(Wh, Wh_bf, 1024 * 1024);
    cvt_f32_bf16<<<1024, 256, 0, stream>>>(Ws, Ws_bf, 1024 * 1024);

    dec_gemm<<<8, 256, 0, stream>>>(hd, cd, Ws_bf, Wsb, dec_feat);

    attn_score_gemm<<<dim3(8, 512), 256, 0, stream>>>(enc, Wh_bf, dec_feat, cov, wcw, vw, score);

    softmax_kernel<<<128, 512, 0, stream>>>(score, mask, cov, aw, ncov);

    context_kernel<<<dim3(4, 128), 256, 0, stream>>>(enc, aw, ctx);
}

// Round 2
// 740.425 us; speedup vs baseline: 1.0298x; 1.0298x over previous
//
#include <hip/hip_runtime.h>
#include <hip/hip_bf16.h>
#include <cstdint>
#include <cstddef>

// Problem: B=128, S=512, H=512, D=1024
// Outputs (flat in d_out): context (128*1024) | aw (128*512) | new_coverage (128*512)

typedef __attribute__((ext_vector_type(8))) short bf16x8;
typedef __attribute__((ext_vector_type(4))) float f32x4;

#define GLOBAL_AS(p) ((const __attribute__((address_space(1))) unsigned int*)(p))
#define LDS_AS(p)    ((__attribute__((address_space(3))) unsigned int*)(p))

__device__ __forceinline__ short f2bf(float f) {
    union { float f; uint32_t u; } v; v.f = f;
    uint32_t u = v.u + 0x7fffu + ((v.u >> 16) & 1u);  // RNE
    return (short)(u >> 16);
}

__device__ __forceinline__ float bf2f(short s) {
    union { uint32_t u; float f; } v; v.u = ((uint32_t)(uint16_t)s) << 16;
    return v.f;
}

__device__ __forceinline__ bf16x8 cvt8(float4 a, float4 b) {
    bf16x8 r;
    r[0] = f2bf(a.x); r[1] = f2bf(a.y); r[2] = f2bf(a.z); r[3] = f2bf(a.w);
    r[4] = f2bf(b.x); r[5] = f2bf(b.y); r[6] = f2bf(b.z); r[7] = f2bf(b.w);
    return r;
}

__device__ __forceinline__ float fast_tanh(float x) {
    x = fminf(10.f, fmaxf(-10.f, x));
    float e = __expf(2.f * x);
    return (e - 1.f) / (e + 1.f);
}

// ---------------- unified fp32 -> bf16 conversion: [enc | Wh | Ws] -------------
// Each thread converts 8 elements (two float4 loads, one 16B store).
__global__ __launch_bounds__(256) void cvt_all(
    const float* __restrict__ enc, const float* __restrict__ Wh, const float* __restrict__ Ws,
    short* __restrict__ enc_bf, short* __restrict__ Wh_bf, short* __restrict__ Ws_bf)
{
    size_t i = ((size_t)blockIdx.x * 256 + threadIdx.x) * 8;
    const float* src; short* dst; size_t off;
    const size_t NE = 67108864;   // 128*512*1024
    const size_t NW = 1048576;    // 1024*1024
    if (i < NE)            { src = enc; dst = enc_bf; off = i; }
    else if (i < NE + NW)  { src = Wh;  dst = Wh_bf;  off = i - NE; }
    else                   { src = Ws;  dst = Ws_bf;  off = i - NE - NW; }
    float4 a = *(const float4*)(src + off);
    float4 b = *(const float4*)(src + off + 4);
    *(bf16x8*)(dst + off) = cvt8(a, b);
}

// small cvt for fallback path (weights only)
__global__ void cvt_f32_bf16(const float* __restrict__ src, short* __restrict__ dst, int n) {
    int i = (blockIdx.x * 256 + threadIdx.x) * 4;
    if (i < n) {
        float4 f = *(const float4*)(src + i);
        short4 o;
        o.x = f2bf(f.x); o.y = f2bf(f.y); o.z = f2bf(f.z); o.w = f2bf(f.w);
        *(short4*)(dst + i) = o;
    }
}

// ---------------- dec_feat = s_t @ Ws^T + Ws_b  (M=128, N=1024, K=1024) --------
__global__ __launch_bounds__(256) void dec_gemm(
    const float* __restrict__ hd, const float* __restrict__ cd,
    const short* __restrict__ Ws, const float* __restrict__ Wsb,
    float* __restrict__ dec_feat)
{
    __shared__ __align__(16) short As[128 * 40];
    __shared__ __align__(16) short Bs[128 * 40];
    const int t = threadIdx.x;
    const int bx = blockIdx.x;                 // n-tile 0..7
    const int wv = t >> 6, lane = t & 63, q = lane >> 4, c = lane & 15;
    const int wm = wv & 1, wn = wv >> 1;
    const int ar = t >> 1, ah = t & 1;

    const short* bptr = Ws + ((size_t)(bx * 128 + ar)) * 1024 + ah * 16;
    short* awr = &As[ar * 40 + ah * 16];
    short* bwr = &Bs[ar * 40 + ah * 16];

    f32x4 acc[4][4];
#pragma unroll
    for (int i = 0; i < 4; ++i)
#pragma unroll
        for (int j = 0; j < 4; ++j) acc[i][j] = (f32x4){0.f, 0.f, 0.f, 0.f};

    for (int k0 = 0; k0 < 1024; k0 += 32) {
        const int k = k0 + ah * 16;
        const float* src = (k < 512) ? (hd + (size_t)ar * 512 + k)
                                     : (cd + (size_t)ar * 512 + (k - 512));
        const float4* ap = (const float4*)src;
        float4 a0 = ap[0], a1 = ap[1], a2 = ap[2], a3 = ap[3];
        bf16x8 bv0 = *(const bf16x8*)(bptr + k0);
        bf16x8 bv1 = *(const bf16x8*)(bptr + k0 + 8);
        *(bf16x8*)awr = cvt8(a0, a1);
        *(bf16x8*)(awr + 8) = cvt8(a2, a3);
        *(bf16x8*)bwr = bv0;
        *(bf16x8*)(bwr + 8) = bv1;
        __syncthreads();
        bf16x8 af[4], bf[4];
#pragma unroll
        for (int i = 0; i < 4; ++i) af[i] = *(const bf16x8*)&As[(wm * 64 + i * 16 + c) * 40 + q * 8];
#pragma unroll
        for (int j = 0; j < 4; ++j) bf[j] = *(const bf16x8*)&Bs[(wn * 64 + j * 16 + c) * 40 + q * 8];
#pragma unroll
        for (int i = 0; i < 4; ++i)
#pragma unroll
            for (int j = 0; j < 4; ++j)
                acc[i][j] = __builtin_amdgcn_mfma_f32_16x16x32_bf16(af[i], bf[j], acc[i][j], 0, 0, 0);
        __syncthreads();
    }

    const int n0 = bx * 128 + wn * 64;
    float wsb_e[4];
#pragma unroll
    for (int j = 0; j < 4; ++j) wsb_e[j] = Wsb[n0 + j * 16 + c];
#pragma unroll
    for (int i = 0; i < 4; ++i)
#pragma unroll
        for (int rr = 0; rr < 4; ++rr) {
            int bidx = wm * 64 + i * 16 + q * 4 + rr;
#pragma unroll
            for (int j = 0; j < 4; ++j) {
                int e = n0 + j * 16 + c;
                dec_feat[(size_t)bidx * 1024 + e] = acc[i][j][rr] + wsb_e[j];
            }
        }
}

// ---------------- main score GEMM, m97-style (bf16 A + B, global_load_lds) -----
// M = B*S = 65536, N = 1024 (e), K = 1024 (d).
// p_part[slice][b][s], slice = bx*2 + wn  (16 slices)
__global__ __launch_bounds__(256) void attn_score_gemm2(
    const short* __restrict__ encb, const short* __restrict__ Whb,
    const float* __restrict__ dec_feat, const float* __restrict__ cov,
    const float* __restrict__ wc_w, const float* __restrict__ v_w,
    float* __restrict__ p_part)
{
    __shared__ __align__(16) short As[128 * 32];  // 8 KB, unpadded (global_load_lds layout)
    __shared__ __align__(16) short Bs[128 * 32];  // 8 KB
    const int t = threadIdx.x;
    const int bx = blockIdx.x;                 // n-tile 0..7 (fast -> A-tile LLC reuse)
    const int by = blockIdx.y;                 // m-tile 0..511
    const int b  = by >> 2;
    const int s0 = (by & 3) * 128;

    const int wv = t >> 6, lane = t & 63, q = lane >> 4, c = lane & 15;
    const int wm = wv & 1, wn = wv >> 1;

    // staging: wave wv covers rows [wv*16, wv*16+16), lane l -> row wv*16 + l/4, col (l&3)*8 elems
    const int srow = wv * 16 + (lane >> 2);
    const int scol = (lane & 3) * 8;
    const short* ag0 = encb + ((size_t)(by * 128 + srow)) * 1024 + scol;
    const short* ag1 = ag0 + (size_t)64 * 1024;
    const short* bg0 = Whb + ((size_t)(bx * 128 + srow)) * 1024 + scol;
    const short* bg1 = bg0 + (size_t)64 * 1024;
    // wave-uniform LDS bases: wave wv's 16 rows start at wv*16*32 elems = wv*512
    short* al0 = &As[wv * 512];
    short* al1 = &As[64 * 32 + wv * 512];
    short* bl0 = &Bs[wv * 512];
    short* bl1 = &Bs[64 * 32 + wv * 512];

    f32x4 acc[4][4];
#pragma unroll
    for (int i = 0; i < 4; ++i)
#pragma unroll
        for (int j = 0; j < 4; ++j) acc[i][j] = (f32x4){0.f, 0.f, 0.f, 0.f};

    for (int k0 = 0; k0 < 1024; k0 += 32) {
        __builtin_amdgcn_global_load_lds(GLOBAL_AS(ag0 + k0), LDS_AS(al0), 16, 0, 0);
        __builtin_amdgcn_global_load_lds(GLOBAL_AS(ag1 + k0), LDS_AS(al1), 16, 0, 0);
        __builtin_amdgcn_global_load_lds(GLOBAL_AS(bg0 + k0), LDS_AS(bl0), 16, 0, 0);
        __builtin_amdgcn_global_load_lds(GLOBAL_AS(bg1 + k0), LDS_AS(bl1), 16, 0, 0);
        __syncthreads();
        bf16x8 af[4], bf[4];
#pragma unroll
        for (int i = 0; i < 4; ++i) af[i] = *(const bf16x8*)&As[(wm * 64 + i * 16 + c) * 32 + q * 8];
#pragma unroll
        for (int j = 0; j < 4; ++j) bf[j] = *(const bf16x8*)&Bs[(wn * 64 + j * 16 + c) * 32 + q * 8];
#pragma unroll
        for (int i = 0; i < 4; ++i)
#pragma unroll
            for (int j = 0; j < 4; ++j)
                acc[i][j] = __builtin_amdgcn_mfma_f32_16x16x32_bf16(af[i], bf[j], acc[i][j], 0, 0, 0);
        __syncthreads();
    }

    // Epilogue: p = sum_e v[e]*tanh(acc + dec_feat[b,e] + cov[b,s]*wc[e]) over this block's e-range
    const int n0 = bx * 128 + wn * 64;
    float v_e[4], wc_e[4], dec_e[4];
#pragma unroll
    for (int j = 0; j < 4; ++j) {
        int e = n0 + j * 16 + c;
        v_e[j]  = v_w[e];
        wc_e[j] = wc_w[e];
        dec_e[j] = dec_feat[(size_t)b * 1024 + e];
    }
    const float* covb = cov + (size_t)b * 512;
    float* pp = p_part + ((size_t)(bx * 2 + wn)) * 65536 + (size_t)b * 512;
#pragma unroll
    for (int i = 0; i < 4; ++i)
#pragma unroll
        for (int rr = 0; rr < 4; ++rr) {
            int s = s0 + wm * 64 + i * 16 + q * 4 + rr;
            float cs = covb[s];
            float p = 0.f;
#pragma unroll
            for (int j = 0; j < 4; ++j) {
                float att = acc[i][j][rr] + dec_e[j] + cs * wc_e[j];
                p += v_e[j] * fast_tanh(att);
            }
            p += __shfl_xor(p, 1);
            p += __shfl_xor(p, 2);
            p += __shfl_xor(p, 4);
            p += __shfl_xor(p, 8);
            if (c == 0) pp[s] = p;
        }
}

// ---------------- fallback score GEMM (fp32 A, register cvt) -------------------
__global__ __launch_bounds__(256) void attn_score_gemm_fb(
    const float* __restrict__ enc, const short* __restrict__ Wh,
    const float* __restrict__ dec_feat, const float* __restrict__ cov,
    const float* __restrict__ wc_w, const float* __restrict__ v_w,
    float* __restrict__ p_part)
{
    __shared__ __align__(16) short As[128 * 40];
    __shared__ __align__(16) short Bs[128 * 40];
    const int t = threadIdx.x;
    const int bx = blockIdx.x;
    const int by = blockIdx.y;
    const int b  = by >> 2;
    const int s0 = (by & 3) * 128;

    const int wv = t >> 6, lane = t & 63, q = lane >> 4, c = lane & 15;
    const int wm = wv & 1, wn = wv >> 1;
    const int ar = t >> 1, ah = t & 1;

    const float* aptr = enc + ((size_t)(by * 128 + ar)) * 1024 + ah * 16;
    const short* bptr = Wh + ((size_t)(bx * 128 + ar)) * 1024 + ah * 16;
    short* awr = &As[ar * 40 + ah * 16];
    short* bwr = &Bs[ar * 40 + ah * 16];

    f32x4 acc[4][4];
#pragma unroll
    for (int i = 0; i < 4; ++i)
#pragma unroll
        for (int j = 0; j < 4; ++j) acc[i][j] = (f32x4){0.f, 0.f, 0.f, 0.f};

    for (int k0 = 0; k0 < 1024; k0 += 32) {
        const float4* ap = (const float4*)(aptr + k0);
        float4 a0 = ap[0], a1 = ap[1], a2 = ap[2], a3 = ap[3];
        bf16x8 bv0 = *(const bf16x8*)(bptr + k0);
        bf16x8 bv1 = *(const bf16x8*)(bptr + k0 + 8);
        *(bf16x8*)awr = cvt8(a0, a1);
        *(bf16x8*)(awr + 8) = cvt8(a2, a3);
        *(bf16x8*)bwr = bv0;
        *(bf16x8*)(bwr + 8) = bv1;
        __syncthreads();
        bf16x8 af[4], bf[4];
#pragma unroll
        for (int i = 0; i < 4; ++i) af[i] = *(const bf16x8*)&As[(wm * 64 + i * 16 + c) * 40 + q * 8];
#pragma unroll
        for (int j = 0; j < 4; ++j) bf[j] = *(const bf16x8*)&Bs[(wn * 64 + j * 16 + c) * 40 + q * 8];
#pragma unroll
        for (int i = 0; i < 4; ++i)
#pragma unroll
            for (int j = 0; j < 4; ++j)
                acc[i][j] = __builtin_amdgcn_mfma_f32_16x16x32_bf16(af[i], bf[j], acc[i][j], 0, 0, 0);
        __syncthreads();
    }

    const int n0 = bx * 128 + wn * 64;
    float v_e[4], wc_e[4], dec_e[4];
#pragma unroll
    for (int j = 0; j < 4; ++j) {
        int e = n0 + j * 16 + c;
        v_e[j]  = v_w[e];
        wc_e[j] = wc_w[e];
        dec_e[j] = dec_feat[(size_t)b * 1024 + e];
    }
    const float* covb = cov + (size_t)b * 512;
    float* pp = p_part + ((size_t)(bx * 2 + wn)) * 65536 + (size_t)b * 512;
#pragma unroll
    for (int i = 0; i < 4; ++i)
#pragma unroll
        for (int rr = 0; rr < 4; ++rr) {
            int s = s0 + wm * 64 + i * 16 + q * 4 + rr;
            float cs = covb[s];
            float p = 0.f;
#pragma unroll
            for (int j = 0; j < 4; ++j) {
                float att = acc[i][j][rr] + dec_e[j] + cs * wc_e[j];
                p += v_e[j] * fast_tanh(att);
            }
            p += __shfl_xor(p, 1);
            p += __shfl_xor(p, 2);
            p += __shfl_xor(p, 4);
            p += __shfl_xor(p, 8);
            if (c == 0) pp[s] = p;
        }
}

// ---------------- softmax: sum 16 partials, masked softmax + renorm ------------
__global__ __launch_bounds__(512) void softmax_kernel(
    const float* __restrict__ p_part, const float* __restrict__ mask,
    const float* __restrict__ cov, float* __restrict__ aw, float* __restrict__ ncov)
{
    __shared__ float red[8];
    const int b = blockIdx.x, t = threadIdx.x;
    const int w = t >> 6, lane = t & 63;
    const size_t idx = (size_t)b * 512 + t;

    float sc = 0.f;
#pragma unroll
    for (int k = 0; k < 16; ++k) sc += p_part[(size_t)k * 65536 + idx];

    float m = sc;
#pragma unroll
    for (int o = 1; o < 64; o <<= 1) m = fmaxf(m, __shfl_xor(m, o));
    if (lane == 0) red[w] = m;
    __syncthreads();
#pragma unroll
    for (int i = 0; i < 8; ++i) m = fmaxf(m, red[i]);
    __syncthreads();

    float e = __expf(sc - m);
    float s = e;
#pragma unroll
    for (int o = 1; o < 64; o <<= 1) s += __shfl_xor(s, o);
    if (lane == 0) red[w] = s;
    __syncthreads();
    s = 0.f;
#pragma unroll
    for (int i = 0; i < 8; ++i) s += red[i];
    __syncthreads();

    float wv = (e / s) * mask[idx];
    float s2 = wv;
#pragma unroll
    for (int o = 1; o < 64; o <<= 1) s2 += __shfl_xor(s2, o);
    if (lane == 0) red[w] = s2;
    __syncthreads();
    s2 = 0.f;
#pragma unroll
    for (int i = 0; i < 8; ++i) s2 += red[i];

    float awv = wv / s2;
    aw[idx] = awv;
    ncov[idx] = cov[idx] + awv;
}

// ---------------- context from bf16 encoder ------------------------------------
__global__ __launch_bounds__(256) void context_bf16(
    const short* __restrict__ encb, const float* __restrict__ aw, float* __restrict__ ctx)
{
    const int schunk = blockIdx.x;  // 0..3
    const int b = blockIdx.y;       // 0..127
    const int t = threadIdx.x;
    const int d0 = (t & 127) * 8;   // 128 lanes cover D=1024 as 8-elem chunks
    const int so = t >> 7;          // 0..1: two s-interleaved halves
    const short* ebase = encb + ((size_t)(b * 512 + schunk * 128 + so)) * 1024 + d0;
    const float* awp = aw + (size_t)b * 512 + schunk * 128 + so;
    float acc[8];
#pragma unroll
    for (int i = 0; i < 8; ++i) acc[i] = 0.f;
#pragma unroll 4
    for (int s = 0; s < 128; s += 2) {
        float w = awp[s];
        bf16x8 e = *(const bf16x8*)(ebase + (size_t)s * 1024);
#pragma unroll
        for (int i = 0; i < 8; ++i) acc[i] += w * bf2f(e[i]);
    }
    float* cp = ctx + (size_t)b * 1024 + d0;
#pragma unroll
    for (int i = 0; i < 8; ++i) atomicAdd(cp + i, acc[i]);
}

// fp32 fallback context
__global__ __launch_bounds__(256) void context_f32(
    const float* __restrict__ enc, const float* __restrict__ aw, float* __restrict__ ctx)
{
    const int schunk = blockIdx.x;
    const int b = blockIdx.y;
    const int t = threadIdx.x;
    const float* ebase = enc + ((size_t)(b * 512 + schunk * 128)) * 1024 + t * 4;
    const float* awp = aw + (size_t)b * 512 + schunk * 128;
    float ax = 0.f, ay = 0.f, az = 0.f, aww = 0.f;
#pragma unroll 4
    for (int s = 0; s < 128; ++s) {
        float w = awp[s];
        float4 e4 = *(const float4*)(ebase + (size_t)s * 1024);
        ax += w * e4.x; ay += w * e4.y; az += w * e4.z; aww += w * e4.w;
    }
    float* cp = ctx + (size_t)b * 1024 + t * 4;
    atomicAdd(cp + 0, ax);
    atomicAdd(cp + 1, ay);
    atomicAdd(cp + 2, az);
    atomicAdd(cp + 3, aww);
}

extern "C" void kernel_launch(void* const* d_in, const int* in_sizes, int n_in,
                              void* d_out, int out_size, void* d_ws, size_t ws_size,
                              hipStream_t stream) {
    const float* hd   = (const float*)d_in[0];
    const float* cd   = (const float*)d_in[1];
    const float* enc  = (const float*)d_in[2];
    const float* mask = (const float*)d_in[3];
    const float* cov  = (const float*)d_in[4];
    const float* Wh   = (const float*)d_in[5];
    const float* Ws   = (const float*)d_in[6];
    const float* Wsb  = (const float*)d_in[7];
    const float* vw   = (const float*)d_in[8];
    const float* wcw  = (const float*)d_in[9];

    float* out  = (float*)d_out;
    float* ctx  = out;
    float* aw   = out + 131072;
    float* ncov = out + 196608;

    // ws layout: p_part 4MB | dec_feat 512KB | Wh_bf 2MB | Ws_bf 2MB | enc_bf 128MB
    char* ws = (char*)d_ws;
    float* p_part   = (float*)ws;                                   // 16*65536*4 = 4 MB
    float* dec_feat = (float*)(ws + (4u << 20));                    // 512 KB
    short* Wh_bf    = (short*)(ws + (4u << 20) + (512u << 10));     // 2 MB
    short* Ws_bf    = (short*)(ws + (6u << 20) + (512u << 10));     // 2 MB
    short* enc_bf   = (short*)(ws + (8u << 20) + (512u << 10));     // 128 MB
    const size_t need_big = (8ull << 20) + (512ull << 10) + (128ull << 20);

    hipMemsetAsync(ctx, 0, 128 * 1024 * sizeof(float), stream);

    if (ws_size >= need_big) {
        // convert enc + Wh + Ws in one pass: (67108864 + 2097152)/8/256 = 33792 blocks
        cvt_all<<<33792, 256, 0, stream>>>(enc, Wh, Ws, enc_bf, Wh_bf, Ws_bf);
        dec_gemm<<<8, 256, 0, stream>>>(hd, cd, Ws_bf, Wsb, dec_feat);
        attn_score_gemm2<<<dim3(8, 512), 256, 0, stream>>>(enc_bf, Wh_bf, dec_feat, cov, wcw, vw, p_part);
        softmax_kernel<<<128, 512, 0, stream>>>(p_part, mask, cov, aw, ncov);
        context_bf16<<<dim3(4, 128), 256, 0, stream>>>(enc_bf, aw, ctx);
    } else {
        cvt_f32_bf16<<<1024, 256, 0, stream>>>(Wh, Wh_bf, 1024 * 1024);
        cvt_f32_bf16<<<1024, 256, 0, stream>>>(Ws, Ws_bf, 1024 * 1024);
        dec_gemm<<<8, 256, 0, stream>>>(hd, cd, Ws_bf, Wsb, dec_feat);
        attn_score_gemm_fb<<<dim3(8, 512), 256, 0, stream>>>(enc, Wh_bf, dec_feat, cov, wcw, vw, p_part);
        softmax_kernel<<<128, 512, 0, stream>>>(p_part, mask, cov, aw, ncov);
        context_f32<<<dim3(4, 128), 256, 0, stream>>>(enc, aw, ctx);
    }
}

// Round 3
// 734.872 us; speedup vs baseline: 1.0375x; 1.0076x over previous
//
#include <hip/hip_runtime.h>
#include <hip/hip_bf16.h>
#include <cstdint>
#include <cstddef>

// Problem: B=128, S=512, H=512, D=1024
// Outputs (flat in d_out): context (128*1024) | aw (128*512) | new_coverage (128*512)

typedef __attribute__((ext_vector_type(8))) short bf16x8;
typedef __attribute__((ext_vector_type(4))) float f32x4;

#define GLOBAL_AS(p) ((const __attribute__((address_space(1))) unsigned int*)(p))
#define LDS_AS(p)    ((__attribute__((address_space(3))) unsigned int*)(p))

__device__ __forceinline__ short f2bf(float f) {
    union { float f; uint32_t u; } v; v.f = f;
    uint32_t u = v.u + 0x7fffu + ((v.u >> 16) & 1u);  // RNE
    return (short)(u >> 16);
}

__device__ __forceinline__ float bf2f(short s) {
    union { uint32_t u; float f; } v; v.u = ((uint32_t)(uint16_t)s) << 16;
    return v.f;
}

__device__ __forceinline__ bf16x8 cvt8(float4 a, float4 b) {
    bf16x8 r;
    r[0] = f2bf(a.x); r[1] = f2bf(a.y); r[2] = f2bf(a.z); r[3] = f2bf(a.w);
    r[4] = f2bf(b.x); r[5] = f2bf(b.y); r[6] = f2bf(b.z); r[7] = f2bf(b.w);
    return r;
}

__device__ __forceinline__ float fast_tanh(float x) {
    x = fminf(10.f, fmaxf(-10.f, x));
    float e = __expf(2.f * x);
    return (e - 1.f) / (e + 1.f);
}

// ---------------- unified fp32 -> bf16 conversion: [enc | Wh | Ws] -------------
__global__ __launch_bounds__(256) void cvt_all(
    const float* __restrict__ enc, const float* __restrict__ Wh, const float* __restrict__ Ws,
    short* __restrict__ enc_bf, short* __restrict__ Wh_bf, short* __restrict__ Ws_bf)
{
    size_t i = ((size_t)blockIdx.x * 256 + threadIdx.x) * 8;
    const float* src; short* dst; size_t off;
    const size_t NE = 67108864;   // 128*512*1024
    const size_t NW = 1048576;    // 1024*1024
    if (i < NE)            { src = enc; dst = enc_bf; off = i; }
    else if (i < NE + NW)  { src = Wh;  dst = Wh_bf;  off = i - NE; }
    else                   { src = Ws;  dst = Ws_bf;  off = i - NE - NW; }
    float4 a = *(const float4*)(src + off);
    float4 b = *(const float4*)(src + off + 4);
    *(bf16x8*)(dst + off) = cvt8(a, b);
}

// small cvt for fallback path (weights only)
__global__ void cvt_f32_bf16(const float* __restrict__ src, short* __restrict__ dst, int n) {
    int i = (blockIdx.x * 256 + threadIdx.x) * 4;
    if (i < n) {
        float4 f = *(const float4*)(src + i);
        short4 o;
        o.x = f2bf(f.x); o.y = f2bf(f.y); o.z = f2bf(f.z); o.w = f2bf(f.w);
        *(short4*)(dst + i) = o;
    }
}

// ---------------- dec_feat = s_t @ Ws^T + Ws_b  (M=128, N=1024, K=1024) --------
__global__ __launch_bounds__(256) void dec_gemm(
    const float* __restrict__ hd, const float* __restrict__ cd,
    const short* __restrict__ Ws, const float* __restrict__ Wsb,
    float* __restrict__ dec_feat)
{
    __shared__ __align__(16) short As[128 * 40];
    __shared__ __align__(16) short Bs[128 * 40];
    const int t = threadIdx.x;
    const int bx = blockIdx.x;                 // n-tile 0..7
    const int wv = t >> 6, lane = t & 63, q = lane >> 4, c = lane & 15;
    const int wm = wv & 1, wn = wv >> 1;
    const int ar = t >> 1, ah = t & 1;

    const short* bptr = Ws + ((size_t)(bx * 128 + ar)) * 1024 + ah * 16;
    short* awr = &As[ar * 40 + ah * 16];
    short* bwr = &Bs[ar * 40 + ah * 16];

    f32x4 acc[4][4];
#pragma unroll
    for (int i = 0; i < 4; ++i)
#pragma unroll
        for (int j = 0; j < 4; ++j) acc[i][j] = (f32x4){0.f, 0.f, 0.f, 0.f};

    for (int k0 = 0; k0 < 1024; k0 += 32) {
        const int k = k0 + ah * 16;
        const float* src = (k < 512) ? (hd + (size_t)ar * 512 + k)
                                     : (cd + (size_t)ar * 512 + (k - 512));
        const float4* ap = (const float4*)src;
        float4 a0 = ap[0], a1 = ap[1], a2 = ap[2], a3 = ap[3];
        bf16x8 bv0 = *(const bf16x8*)(bptr + k0);
        bf16x8 bv1 = *(const bf16x8*)(bptr + k0 + 8);
        *(bf16x8*)awr = cvt8(a0, a1);
        *(bf16x8*)(awr + 8) = cvt8(a2, a3);
        *(bf16x8*)bwr = bv0;
        *(bf16x8*)(bwr + 8) = bv1;
        __syncthreads();
        bf16x8 af[4], bf[4];
#pragma unroll
        for (int i = 0; i < 4; ++i) af[i] = *(const bf16x8*)&As[(wm * 64 + i * 16 + c) * 40 + q * 8];
#pragma unroll
        for (int j = 0; j < 4; ++j) bf[j] = *(const bf16x8*)&Bs[(wn * 64 + j * 16 + c) * 40 + q * 8];
#pragma unroll
        for (int i = 0; i < 4; ++i)
#pragma unroll
            for (int j = 0; j < 4; ++j)
                acc[i][j] = __builtin_amdgcn_mfma_f32_16x16x32_bf16(af[i], bf[j], acc[i][j], 0, 0, 0);
        __syncthreads();
    }

    const int n0 = bx * 128 + wn * 64;
    float wsb_e[4];
#pragma unroll
    for (int j = 0; j < 4; ++j) wsb_e[j] = Wsb[n0 + j * 16 + c];
#pragma unroll
    for (int i = 0; i < 4; ++i)
#pragma unroll
        for (int rr = 0; rr < 4; ++rr) {
            int bidx = wm * 64 + i * 16 + q * 4 + rr;
#pragma unroll
            for (int j = 0; j < 4; ++j) {
                int e = n0 + j * 16 + c;
                dec_feat[(size_t)bidx * 1024 + e] = acc[i][j][rr] + wsb_e[j];
            }
        }
}

// ---------------- main score GEMM: XCD-aware grid + XOR-swizzled LDS -----------
// M = B*S = 65536, N = 1024 (e), K = 1024 (d). 1D grid of 4096 blocks.
// Grid remap: lin&7 selects XCD-affine m-group so all 8 n-tiles of one A-tile
// land on one XCD (L2 reuse). LDS swizzle: colgroup g stored at g^((row^(row>>2))&3)
// -> fragment ds_read_b128 is 2-way conflict (free) instead of 8-way.
__global__ __launch_bounds__(256) void attn_score_gemm3(
    const short* __restrict__ encb, const short* __restrict__ Whb,
    const float* __restrict__ dec_feat, const float* __restrict__ cov,
    const float* __restrict__ wc_w, const float* __restrict__ v_w,
    float* __restrict__ p_part)
{
    __shared__ __align__(16) short As[128 * 32];  // 8 KB
    __shared__ __align__(16) short Bs[128 * 32];  // 8 KB
    const int t = threadIdx.x;
    const int lin = blockIdx.x;
    const int xcd = lin & 7;
    const int kk  = lin >> 3;
    const int bx  = kk & 7;                    // n-tile (fast within XCD)
    const int by  = xcd * 64 + (kk >> 3);      // m-tile
    const int b   = by >> 2;
    const int s0  = (by & 3) * 128;

    const int wv = t >> 6, lane = t & 63, q = lane >> 4, c = lane & 15;
    const int wm = wv & 1, wn = wv >> 1;

    // staging: lane l -> row wv*16 + l/4, LDS slot (l&3); global colgroup swizzled
    const int srow = wv * 16 + (lane >> 2);
    const int gg = (lane & 3) ^ ((srow ^ (srow >> 2)) & 3);
    const short* ag0 = encb + ((size_t)(by * 128 + srow)) * 1024 + gg * 8;
    const short* ag1 = ag0 + (size_t)64 * 1024;
    const short* bg0 = Whb + ((size_t)(bx * 128 + srow)) * 1024 + gg * 8;
    const short* bg1 = bg0 + (size_t)64 * 1024;
    short* al0 = &As[wv * 512];
    short* al1 = &As[64 * 32 + wv * 512];
    short* bl0 = &Bs[wv * 512];
    short* bl1 = &Bs[64 * 32 + wv * 512];

    // fragment-read swizzle (row = ..*16 + c  =>  s(row) = (c ^ (c>>2)) & 3)
    const int qa = (q ^ ((c ^ (c >> 2)) & 3)) * 8;

    f32x4 acc[4][4];
#pragma unroll
    for (int i = 0; i < 4; ++i)
#pragma unroll
        for (int j = 0; j < 4; ++j) acc[i][j] = (f32x4){0.f, 0.f, 0.f, 0.f};

    for (int k0 = 0; k0 < 1024; k0 += 32) {
        __builtin_amdgcn_global_load_lds(GLOBAL_AS(ag0 + k0), LDS_AS(al0), 16, 0, 0);
        __builtin_amdgcn_global_load_lds(GLOBAL_AS(ag1 + k0), LDS_AS(al1), 16, 0, 0);
        __builtin_amdgcn_global_load_lds(GLOBAL_AS(bg0 + k0), LDS_AS(bl0), 16, 0, 0);
        __builtin_amdgcn_global_load_lds(GLOBAL_AS(bg1 + k0), LDS_AS(bl1), 16, 0, 0);
        __syncthreads();
        bf16x8 af[4], bf[4];
#pragma unroll
        for (int i = 0; i < 4; ++i) af[i] = *(const bf16x8*)&As[(wm * 64 + i * 16 + c) * 32 + qa];
#pragma unroll
        for (int j = 0; j < 4; ++j) bf[j] = *(const bf16x8*)&Bs[(wn * 64 + j * 16 + c) * 32 + qa];
#pragma unroll
        for (int i = 0; i < 4; ++i)
#pragma unroll
            for (int j = 0; j < 4; ++j)
                acc[i][j] = __builtin_amdgcn_mfma_f32_16x16x32_bf16(af[i], bf[j], acc[i][j], 0, 0, 0);
        __syncthreads();
    }

    // Epilogue: p = sum_e v[e]*tanh(acc + dec_feat[b,e] + cov[b,s]*wc[e])
    const int n0 = bx * 128 + wn * 64;
    float v_e[4], wc_e[4], dec_e[4];
#pragma unroll
    for (int j = 0; j < 4; ++j) {
        int e = n0 + j * 16 + c;
        v_e[j]  = v_w[e];
        wc_e[j] = wc_w[e];
        dec_e[j] = dec_feat[(size_t)b * 1024 + e];
    }
    const float* covb = cov + (size_t)b * 512;
    float* pp = p_part + ((size_t)(bx * 2 + wn)) * 65536 + (size_t)b * 512;
#pragma unroll
    for (int i = 0; i < 4; ++i)
#pragma unroll
        for (int rr = 0; rr < 4; ++rr) {
            int s = s0 + wm * 64 + i * 16 + q * 4 + rr;
            float cs = covb[s];
            float p = 0.f;
#pragma unroll
            for (int j = 0; j < 4; ++j) {
                float att = acc[i][j][rr] + dec_e[j] + cs * wc_e[j];
                p += v_e[j] * fast_tanh(att);
            }
            p += __shfl_xor(p, 1);
            p += __shfl_xor(p, 2);
            p += __shfl_xor(p, 4);
            p += __shfl_xor(p, 8);
            if (c == 0) pp[s] = p;
        }
}

// ---------------- fallback score GEMM (fp32 A, register cvt) -------------------
__global__ __launch_bounds__(256) void attn_score_gemm_fb(
    const float* __restrict__ enc, const short* __restrict__ Wh,
    const float* __restrict__ dec_feat, const float* __restrict__ cov,
    const float* __restrict__ wc_w, const float* __restrict__ v_w,
    float* __restrict__ p_part)
{
    __shared__ __align__(16) short As[128 * 40];
    __shared__ __align__(16) short Bs[128 * 40];
    const int t = threadIdx.x;
    const int bx = blockIdx.x;
    const int by = blockIdx.y;
    const int b  = by >> 2;
    const int s0 = (by & 3) * 128;

    const int wv = t >> 6, lane = t & 63, q = lane >> 4, c = lane & 15;
    const int wm = wv & 1, wn = wv >> 1;
    const int ar = t >> 1, ah = t & 1;

    const float* aptr = enc + ((size_t)(by * 128 + ar)) * 1024 + ah * 16;
    const short* bptr = Wh + ((size_t)(bx * 128 + ar)) * 1024 + ah * 16;
    short* awr = &As[ar * 40 + ah * 16];
    short* bwr = &Bs[ar * 40 + ah * 16];

    f32x4 acc[4][4];
#pragma unroll
    for (int i = 0; i < 4; ++i)
#pragma unroll
        for (int j = 0; j < 4; ++j) acc[i][j] = (f32x4){0.f, 0.f, 0.f, 0.f};

    for (int k0 = 0; k0 < 1024; k0 += 32) {
        const float4* ap = (const float4*)(aptr + k0);
        float4 a0 = ap[0], a1 = ap[1], a2 = ap[2], a3 = ap[3];
        bf16x8 bv0 = *(const bf16x8*)(bptr + k0);
        bf16x8 bv1 = *(const bf16x8*)(bptr + k0 + 8);
        *(bf16x8*)awr = cvt8(a0, a1);
        *(bf16x8*)(awr + 8) = cvt8(a2, a3);
        *(bf16x8*)bwr = bv0;
        *(bf16x8*)(bwr + 8) = bv1;
        __syncthreads();
        bf16x8 af[4], bf[4];
#pragma unroll
        for (int i = 0; i < 4; ++i) af[i] = *(const bf16x8*)&As[(wm * 64 + i * 16 + c) * 40 + q * 8];
#pragma unroll
        for (int j = 0; j < 4; ++j) bf[j] = *(const bf16x8*)&Bs[(wn * 64 + j * 16 + c) * 40 + q * 8];
#pragma unroll
        for (int i = 0; i < 4; ++i)
#pragma unroll
            for (int j = 0; j < 4; ++j)
                acc[i][j] = __builtin_amdgcn_mfma_f32_16x16x32_bf16(af[i], bf[j], acc[i][j], 0, 0, 0);
        __syncthreads();
    }

    const int n0 = bx * 128 + wn * 64;
    float v_e[4], wc_e[4], dec_e[4];
#pragma unroll
    for (int j = 0; j < 4; ++j) {
        int e = n0 + j * 16 + c;
        v_e[j]  = v_w[e];
        wc_e[j] = wc_w[e];
        dec_e[j] = dec_feat[(size_t)b * 1024 + e];
    }
    const float* covb = cov + (size_t)b * 512;
    float* pp = p_part + ((size_t)(bx * 2 + wn)) * 65536 + (size_t)b * 512;
#pragma unroll
    for (int i = 0; i < 4; ++i)
#pragma unroll
        for (int rr = 0; rr < 4; ++rr) {
            int s = s0 + wm * 64 + i * 16 + q * 4 + rr;
            float cs = covb[s];
            float p = 0.f;
#pragma unroll
            for (int j = 0; j < 4; ++j) {
                float att = acc[i][j][rr] + dec_e[j] + cs * wc_e[j];
                p += v_e[j] * fast_tanh(att);
            }
            p += __shfl_xor(p, 1);
            p += __shfl_xor(p, 2);
            p += __shfl_xor(p, 4);
            p += __shfl_xor(p, 8);
            if (c == 0) pp[s] = p;
        }
}

// ---------------- softmax: sum 16 partials, masked softmax + renorm ------------
__global__ __launch_bounds__(512) void softmax_kernel(
    const float* __restrict__ p_part, const float* __restrict__ mask,
    const float* __restrict__ cov, float* __restrict__ aw, float* __restrict__ ncov)
{
    __shared__ float red[8];
    const int b = blockIdx.x, t = threadIdx.x;
    const int w = t >> 6, lane = t & 63;
    const size_t idx = (size_t)b * 512 + t;

    float sc = 0.f;
#pragma unroll
    for (int k = 0; k < 16; ++k) sc += p_part[(size_t)k * 65536 + idx];

    float m = sc;
#pragma unroll
    for (int o = 1; o < 64; o <<= 1) m = fmaxf(m, __shfl_xor(m, o));
    if (lane == 0) red[w] = m;
    __syncthreads();
#pragma unroll
    for (int i = 0; i < 8; ++i) m = fmaxf(m, red[i]);
    __syncthreads();

    float e = __expf(sc - m);
    float s = e;
#pragma unroll
    for (int o = 1; o < 64; o <<= 1) s += __shfl_xor(s, o);
    if (lane == 0) red[w] = s;
    __syncthreads();
    s = 0.f;
#pragma unroll
    for (int i = 0; i < 8; ++i) s += red[i];
    __syncthreads();

    float wv = (e / s) * mask[idx];
    float s2 = wv;
#pragma unroll
    for (int o = 1; o < 64; o <<= 1) s2 += __shfl_xor(s2, o);
    if (lane == 0) red[w] = s2;
    __syncthreads();
    s2 = 0.f;
#pragma unroll
    for (int i = 0; i < 8; ++i) s2 += red[i];

    float awv = wv / s2;
    aw[idx] = awv;
    ncov[idx] = cov[idx] + awv;
}

// ---------------- context: partial-sum (no atomics) + reduce -------------------
// cpart[16][128][1024] fp32 (8 MB), slice = sc*2 + si
__global__ __launch_bounds__(256) void context_part(
    const short* __restrict__ encb, const float* __restrict__ aw, float* __restrict__ cpart)
{
    const int sc = blockIdx.x & 7;     // s-chunk of 64
    const int b  = blockIdx.x >> 3;    // 0..127
    const int t  = threadIdx.x;
    const int dl = t & 127;            // d-lane: 8 elems each
    const int si = t >> 7;             // 0..1, s-interleave
    const short* ebase = encb + ((size_t)(b * 512 + sc * 64 + si)) * 1024 + dl * 8;
    const float* awp = aw + (size_t)b * 512 + sc * 64 + si;
    float acc[8];
#pragma unroll
    for (int i = 0; i < 8; ++i) acc[i] = 0.f;
#pragma unroll 16
    for (int s = 0; s < 64; s += 2) {
        float w = awp[s];
        bf16x8 e = *(const bf16x8*)(ebase + (size_t)s * 1024);
#pragma unroll
        for (int i = 0; i < 8; ++i) acc[i] += w * bf2f(e[i]);
    }
    float* cp = cpart + ((size_t)(sc * 2 + si) * 128 + b) * 1024 + dl * 8;
    *(float4*)(cp)     = (float4){acc[0], acc[1], acc[2], acc[3]};
    *(float4*)(cp + 4) = (float4){acc[4], acc[5], acc[6], acc[7]};
}

__global__ __launch_bounds__(256) void ctx_reduce(
    const float* __restrict__ cpart, float* __restrict__ ctx)
{
    int i = blockIdx.x * 256 + threadIdx.x;   // 131072 outputs
    float s = 0.f;
#pragma unroll
    for (int k = 0; k < 16; ++k) s += cpart[(size_t)k * 131072 + i];
    ctx[i] = s;
}

// fp32 fallback context
__global__ __launch_bounds__(256) void context_f32(
    const float* __restrict__ enc, const float* __restrict__ aw, float* __restrict__ ctx)
{
    const int schunk = blockIdx.x;
    const int b = blockIdx.y;
    const int t = threadIdx.x;
    const float* ebase = enc + ((size_t)(b * 512 + schunk * 128)) * 1024 + t * 4;
    const float* awp = aw + (size_t)b * 512 + schunk * 128;
    float ax = 0.f, ay = 0.f, az = 0.f, aww = 0.f;
#pragma unroll 4
    for (int s = 0; s < 128; ++s) {
        float w = awp[s];
        float4 e4 = *(const float4*)(ebase + (size_t)s * 1024);
        ax += w * e4.x; ay += w * e4.y; az += w * e4.z; aww += w * e4.w;
    }
    float* cp = ctx + (size_t)b * 1024 + t * 4;
    atomicAdd(cp + 0, ax);
    atomicAdd(cp + 1, ay);
    atomicAdd(cp + 2, az);
    atomicAdd(cp + 3, aww);
}

extern "C" void kernel_launch(void* const* d_in, const int* in_sizes, int n_in,
                              void* d_out, int out_size, void* d_ws, size_t ws_size,
                              hipStream_t stream) {
    const float* hd   = (const float*)d_in[0];
    const float* cd   = (const float*)d_in[1];
    const float* enc  = (const float*)d_in[2];
    const float* mask = (const float*)d_in[3];
    const float* cov  = (const float*)d_in[4];
    const float* Wh   = (const float*)d_in[5];
    const float* Ws   = (const float*)d_in[6];
    const float* Wsb  = (const float*)d_in[7];
    const float* vw   = (const float*)d_in[8];
    const float* wcw  = (const float*)d_in[9];

    float* out  = (float*)d_out;
    float* ctx  = out;
    float* aw   = out + 131072;
    float* ncov = out + 196608;

    // ws layout: [p_part 4MB | dec_feat 512KB | Wh_bf 2MB | Ws_bf 2MB | enc_bf 128MB]
    // cpart (8MB) overlays [p_part..Ws_bf] — all dead by the time context runs.
    char* ws = (char*)d_ws;
    float* p_part   = (float*)ws;
    float* dec_feat = (float*)(ws + (4u << 20));
    short* Wh_bf    = (short*)(ws + (4u << 20) + (512u << 10));
    short* Ws_bf    = (short*)(ws + (6u << 20) + (512u << 10));
    short* enc_bf   = (short*)(ws + (8u << 20) + (512u << 10));
    float* cpart    = (float*)ws;
    const size_t need_big = (8ull << 20) + (512ull << 10) + (128ull << 20);

    if (ws_size >= need_big) {
        cvt_all<<<33792, 256, 0, stream>>>(enc, Wh, Ws, enc_bf, Wh_bf, Ws_bf);
        dec_gemm<<<8, 256, 0, stream>>>(hd, cd, Ws_bf, Wsb, dec_feat);
        attn_score_gemm3<<<4096, 256, 0, stream>>>(enc_bf, Wh_bf, dec_feat, cov, wcw, vw, p_part);
        softmax_kernel<<<128, 512, 0, stream>>>(p_part, mask, cov, aw, ncov);
        context_part<<<1024, 256, 0, stream>>>(enc_bf, aw, cpart);
        ctx_reduce<<<512, 256, 0, stream>>>(cpart, ctx);
    } else {
        hipMemsetAsync(ctx, 0, 128 * 1024 * sizeof(float), stream);
        cvt_f32_bf16<<<1024, 256, 0, stream>>>(Wh, Wh_bf, 1024 * 1024);
        cvt_f32_bf16<<<1024, 256, 0, stream>>>(Ws, Ws_bf, 1024 * 1024);
        dec_gemm<<<8, 256, 0, stream>>>(hd, cd, Ws_bf, Wsb, dec_feat);
        attn_score_gemm_fb<<<dim3(8, 512), 256, 0, stream>>>(enc, Wh_bf, dec_feat, cov, wcw, vw, p_part);
        softmax_kernel<<<128, 512, 0, stream>>>(p_part, mask, cov, aw, ncov);
        context_f32<<<dim3(4, 128), 256, 0, stream>>>(enc, aw, ctx);
    }
}

// Round 4
// 654.019 us; speedup vs baseline: 1.1658x; 1.1236x over previous
//
#include <hip/hip_runtime.h>
#include <hip/hip_bf16.h>
#include <cstdint>
#include <cstddef>

// Problem: B=128, S=512, H=512, D=1024
// Outputs (flat in d_out): context (128*1024) | aw (128*512) | new_coverage (128*512)

typedef __attribute__((ext_vector_type(8))) short bf16x8;
typedef __attribute__((ext_vector_type(4))) float f32x4;

#define GLOBAL_AS(p) ((const __attribute__((address_space(1))) unsigned int*)(p))
#define LDS_AS(p)    ((__attribute__((address_space(3))) unsigned int*)(p))

__device__ __forceinline__ short f2bf(float f) {
    union { float f; uint32_t u; } v; v.f = f;
    uint32_t u = v.u + 0x7fffu + ((v.u >> 16) & 1u);  // RNE
    return (short)(u >> 16);
}

__device__ __forceinline__ float bf2f(short s) {
    union { uint32_t u; float f; } v; v.u = ((uint32_t)(uint16_t)s) << 16;
    return v.f;
}

__device__ __forceinline__ bf16x8 cvt8(float4 a, float4 b) {
    bf16x8 r;
    r[0] = f2bf(a.x); r[1] = f2bf(a.y); r[2] = f2bf(a.z); r[3] = f2bf(a.w);
    r[4] = f2bf(b.x); r[5] = f2bf(b.y); r[6] = f2bf(b.z); r[7] = f2bf(b.w);
    return r;
}

__device__ __forceinline__ float fast_tanh(float x) {
    x = fminf(10.f, fmaxf(-10.f, x));
    float e = __expf(2.f * x);
    return (e - 1.f) / (e + 1.f);
}

// ---------------- fp32 -> bf16 conversion: [enc | Wh] --------------------------
__global__ __launch_bounds__(256) void cvt_all(
    const float* __restrict__ enc, const float* __restrict__ Wh,
    short* __restrict__ enc_bf, short* __restrict__ Wh_bf)
{
    size_t i = ((size_t)blockIdx.x * 256 + threadIdx.x) * 8;
    const float* src; short* dst; size_t off;
    const size_t NE = 67108864;   // 128*512*1024
    if (i < NE) { src = enc; dst = enc_bf; off = i; }
    else        { src = Wh;  dst = Wh_bf;  off = i - NE; }
    float4 a = *(const float4*)(src + off);
    float4 b = *(const float4*)(src + off + 4);
    *(bf16x8*)(dst + off) = cvt8(a, b);
}

// small cvt for fallback path (weights only)
__global__ void cvt_f32_bf16(const float* __restrict__ src, short* __restrict__ dst, int n) {
    int i = (blockIdx.x * 256 + threadIdx.x) * 4;
    if (i < n) {
        float4 f = *(const float4*)(src + i);
        short4 o;
        o.x = f2bf(f.x); o.y = f2bf(f.y); o.z = f2bf(f.z); o.w = f2bf(f.w);
        *(short4*)(dst + i) = o;
    }
}

// ---------------- dec_part[kc] = s_t[:,kc-slice] @ Ws[:,kc-slice]^T  ------------
// M=128, N=1024, K split 4x256. fp32 inputs, in-register cvt (tiny kernel).
__global__ __launch_bounds__(256) void dec_gemm_sk(
    const float* __restrict__ hd, const float* __restrict__ cd,
    const float* __restrict__ Ws, float* __restrict__ dec_part)
{
    __shared__ __align__(16) short As[128 * 40];
    __shared__ __align__(16) short Bs[128 * 40];
    const int t = threadIdx.x;
    const int bx = blockIdx.x & 7;        // n-tile 0..7
    const int kc = blockIdx.x >> 3;       // k-chunk 0..3
    const int wv = t >> 6, lane = t & 63, q = lane >> 4, c = lane & 15;
    const int wm = wv & 1, wn = wv >> 1;
    const int ar = t >> 1, ah = t & 1;

    const float* abase = ((kc < 2) ? hd : cd) + (size_t)ar * 512 + (kc & 1) * 256 + ah * 16;
    const float* bbase = Ws + ((size_t)(bx * 128 + ar)) * 1024 + kc * 256 + ah * 16;
    short* awr = &As[ar * 40 + ah * 16];
    short* bwr = &Bs[ar * 40 + ah * 16];

    f32x4 acc[4][4];
#pragma unroll
    for (int i = 0; i < 4; ++i)
#pragma unroll
        for (int j = 0; j < 4; ++j) acc[i][j] = (f32x4){0.f, 0.f, 0.f, 0.f};

    for (int k0 = 0; k0 < 256; k0 += 32) {
        const float4* ap = (const float4*)(abase + k0);
        const float4* bp = (const float4*)(bbase + k0);
        float4 a0 = ap[0], a1 = ap[1], a2 = ap[2], a3 = ap[3];
        float4 b0 = bp[0], b1 = bp[1], b2 = bp[2], b3 = bp[3];
        *(bf16x8*)awr = cvt8(a0, a1);
        *(bf16x8*)(awr + 8) = cvt8(a2, a3);
        *(bf16x8*)bwr = cvt8(b0, b1);
        *(bf16x8*)(bwr + 8) = cvt8(b2, b3);
        __syncthreads();
        bf16x8 af[4], bf[4];
#pragma unroll
        for (int i = 0; i < 4; ++i) af[i] = *(const bf16x8*)&As[(wm * 64 + i * 16 + c) * 40 + q * 8];
#pragma unroll
        for (int j = 0; j < 4; ++j) bf[j] = *(const bf16x8*)&Bs[(wn * 64 + j * 16 + c) * 40 + q * 8];
#pragma unroll
        for (int i = 0; i < 4; ++i)
#pragma unroll
            for (int j = 0; j < 4; ++j)
                acc[i][j] = __builtin_amdgcn_mfma_f32_16x16x32_bf16(af[i], bf[j], acc[i][j], 0, 0, 0);
        __syncthreads();
    }

    const int n0 = bx * 128 + wn * 64;
    float* dp = dec_part + (size_t)kc * 131072;
#pragma unroll
    for (int i = 0; i < 4; ++i)
#pragma unroll
        for (int rr = 0; rr < 4; ++rr) {
            int bidx = wm * 64 + i * 16 + q * 4 + rr;
#pragma unroll
            for (int j = 0; j < 4; ++j)
                dp[(size_t)bidx * 1024 + n0 + j * 16 + c] = acc[i][j][rr];
        }
}

// ---------------- main score GEMM: XCD grid + double-buffered LDS --------------
// M=65536, N=1024, K=1024. DMA for iter k+1 issued before compute of iter k;
// the single end-of-iter barrier's vmcnt(0) drain overlaps DMA with MFMA.
__global__ __launch_bounds__(256) void attn_score_gemm4(
    const short* __restrict__ encb, const short* __restrict__ Whb,
    const float* __restrict__ dec_part, const float* __restrict__ Wsb,
    const float* __restrict__ cov,
    const float* __restrict__ wc_w, const float* __restrict__ v_w,
    float* __restrict__ p_part)
{
    __shared__ __align__(16) short As[2][128 * 32];  // 16 KB
    __shared__ __align__(16) short Bs[2][128 * 32];  // 16 KB
    const int t = threadIdx.x;
    const int lin = blockIdx.x;
    const int xcd = lin & 7;
    const int kk  = lin >> 3;
    const int bx  = kk & 7;                    // n-tile (fast within XCD)
    const int by  = xcd * 64 + (kk >> 3);      // m-tile
    const int b   = by >> 2;
    const int s0  = (by & 3) * 128;

    const int wv = t >> 6, lane = t & 63, q = lane >> 4, c = lane & 15;
    const int wm = wv & 1, wn = wv >> 1;

    // staging: lane l -> row wv*16 + l/4, LDS slot (l&3); global colgroup swizzled
    const int srow = wv * 16 + (lane >> 2);
    const int gg = (lane & 3) ^ ((srow ^ (srow >> 2)) & 3);
    const short* ag0 = encb + ((size_t)(by * 128 + srow)) * 1024 + gg * 8;
    const short* ag1 = ag0 + (size_t)64 * 1024;
    const short* bg0 = Whb + ((size_t)(bx * 128 + srow)) * 1024 + gg * 8;
    const short* bg1 = bg0 + (size_t)64 * 1024;
    const int lo = wv * 512;                   // wave-uniform LDS offset (elems)

    // fragment-read swizzle
    const int qa = (q ^ ((c ^ (c >> 2)) & 3)) * 8;

    f32x4 acc[4][4];
#pragma unroll
    for (int i = 0; i < 4; ++i)
#pragma unroll
        for (int j = 0; j < 4; ++j) acc[i][j] = (f32x4){0.f, 0.f, 0.f, 0.f};

    // prologue: stage k-tile 0 into buffer 0
    __builtin_amdgcn_global_load_lds(GLOBAL_AS(ag0), LDS_AS(&As[0][lo]), 16, 0, 0);
    __builtin_amdgcn_global_load_lds(GLOBAL_AS(ag1), LDS_AS(&As[0][2048 + lo]), 16, 0, 0);
    __builtin_amdgcn_global_load_lds(GLOBAL_AS(bg0), LDS_AS(&Bs[0][lo]), 16, 0, 0);
    __builtin_amdgcn_global_load_lds(GLOBAL_AS(bg1), LDS_AS(&Bs[0][2048 + lo]), 16, 0, 0);
    __syncthreads();

    for (int k0 = 0; k0 < 32; ++k0) {
        const int cur = k0 & 1;
        if (k0 < 31) {
            const int nxt = cur ^ 1;
            const int kb = (k0 + 1) * 32;
            __builtin_amdgcn_global_load_lds(GLOBAL_AS(ag0 + kb), LDS_AS(&As[nxt][lo]), 16, 0, 0);
            __builtin_amdgcn_global_load_lds(GLOBAL_AS(ag1 + kb), LDS_AS(&As[nxt][2048 + lo]), 16, 0, 0);
            __builtin_amdgcn_global_load_lds(GLOBAL_AS(bg0 + kb), LDS_AS(&Bs[nxt][lo]), 16, 0, 0);
            __builtin_amdgcn_global_load_lds(GLOBAL_AS(bg1 + kb), LDS_AS(&Bs[nxt][2048 + lo]), 16, 0, 0);
        }
        bf16x8 af[4], bf[4];
#pragma unroll
        for (int i = 0; i < 4; ++i) af[i] = *(const bf16x8*)&As[cur][(wm * 64 + i * 16 + c) * 32 + qa];
#pragma unroll
        for (int j = 0; j < 4; ++j) bf[j] = *(const bf16x8*)&Bs[cur][(wn * 64 + j * 16 + c) * 32 + qa];
#pragma unroll
        for (int i = 0; i < 4; ++i)
#pragma unroll
            for (int j = 0; j < 4; ++j)
                acc[i][j] = __builtin_amdgcn_mfma_f32_16x16x32_bf16(af[i], bf[j], acc[i][j], 0, 0, 0);
        __syncthreads();   // vmcnt(0)+lgkmcnt(0) drain: next-iter DMA done, cur reads done
    }

    // Epilogue: p = sum_e v[e]*tanh(acc + dec[b,e] + cov[b,s]*wc[e])
    const int n0 = bx * 128 + wn * 64;
    float v_e[4], wc_e[4], dec_e[4];
#pragma unroll
    for (int j = 0; j < 4; ++j) {
        int e = n0 + j * 16 + c;
        v_e[j]  = v_w[e];
        wc_e[j] = wc_w[e];
        float d = Wsb[e];
#pragma unroll
        for (int p = 0; p < 4; ++p) d += dec_part[(size_t)p * 131072 + (size_t)b * 1024 + e];
        dec_e[j] = d;
    }
    const float* covb = cov + (size_t)b * 512;
    float* pp = p_part + ((size_t)(bx * 2 + wn)) * 65536 + (size_t)b * 512;
#pragma unroll
    for (int i = 0; i < 4; ++i)
#pragma unroll
        for (int rr = 0; rr < 4; ++rr) {
            int s = s0 + wm * 64 + i * 16 + q * 4 + rr;
            float cs = covb[s];
            float p = 0.f;
#pragma unroll
            for (int j = 0; j < 4; ++j) {
                float att = acc[i][j][rr] + dec_e[j] + cs * wc_e[j];
                p += v_e[j] * fast_tanh(att);
            }
            p += __shfl_xor(p, 1);
            p += __shfl_xor(p, 2);
            p += __shfl_xor(p, 4);
            p += __shfl_xor(p, 8);
            if (c == 0) pp[s] = p;
        }
}

// ---------------- fallback score GEMM (fp32 A, register cvt) -------------------
__global__ __launch_bounds__(256) void attn_score_gemm_fb(
    const float* __restrict__ enc, const short* __restrict__ Wh,
    const float* __restrict__ dec_feat, const float* __restrict__ cov,
    const float* __restrict__ wc_w, const float* __restrict__ v_w,
    float* __restrict__ p_part)
{
    __shared__ __align__(16) short As[128 * 40];
    __shared__ __align__(16) short Bs[128 * 40];
    const int t = threadIdx.x;
    const int bx = blockIdx.x;
    const int by = blockIdx.y;
    const int b  = by >> 2;
    const int s0 = (by & 3) * 128;

    const int wv = t >> 6, lane = t & 63, q = lane >> 4, c = lane & 15;
    const int wm = wv & 1, wn = wv >> 1;
    const int ar = t >> 1, ah = t & 1;

    const float* aptr = enc + ((size_t)(by * 128 + ar)) * 1024 + ah * 16;
    const short* bptr = Wh + ((size_t)(bx * 128 + ar)) * 1024 + ah * 16;
    short* awr = &As[ar * 40 + ah * 16];
    short* bwr = &Bs[ar * 40 + ah * 16];

    f32x4 acc[4][4];
#pragma unroll
    for (int i = 0; i < 4; ++i)
#pragma unroll
        for (int j = 0; j < 4; ++j) acc[i][j] = (f32x4){0.f, 0.f, 0.f, 0.f};

    for (int k0 = 0; k0 < 1024; k0 += 32) {
        const float4* ap = (const float4*)(aptr + k0);
        float4 a0 = ap[0], a1 = ap[1], a2 = ap[2], a3 = ap[3];
        bf16x8 bv0 = *(const bf16x8*)(bptr + k0);
        bf16x8 bv1 = *(const bf16x8*)(bptr + k0 + 8);
        *(bf16x8*)awr = cvt8(a0, a1);
        *(bf16x8*)(awr + 8) = cvt8(a2, a3);
        *(bf16x8*)bwr = bv0;
        *(bf16x8*)(bwr + 8) = bv1;
        __syncthreads();
        bf16x8 af[4], bf[4];
#pragma unroll
        for (int i = 0; i < 4; ++i) af[i] = *(const bf16x8*)&As[(wm * 64 + i * 16 + c) * 40 + q * 8];
#pragma unroll
        for (int j = 0; j < 4; ++j) bf[j] = *(const bf16x8*)&Bs[(wn * 64 + j * 16 + c) * 40 + q * 8];
#pragma unroll
        for (int i = 0; i < 4; ++i)
#pragma unroll
            for (int j = 0; j < 4; ++j)
                acc[i][j] = __builtin_amdgcn_mfma_f32_16x16x32_bf16(af[i], bf[j], acc[i][j], 0, 0, 0);
        __syncthreads();
    }

    const int n0 = bx * 128 + wn * 64;
    float v_e[4], wc_e[4], dec_e[4];
#pragma unroll
    for (int j = 0; j < 4; ++j) {
        int e = n0 + j * 16 + c;
        v_e[j]  = v_w[e];
        wc_e[j] = wc_w[e];
        dec_e[j] = dec_feat[(size_t)b * 1024 + e];
    }
    const float* covb = cov + (size_t)b * 512;
    float* pp = p_part + ((size_t)(bx * 2 + wn)) * 65536 + (size_t)b * 512;
#pragma unroll
    for (int i = 0; i < 4; ++i)
#pragma unroll
        for (int rr = 0; rr < 4; ++rr) {
            int s = s0 + wm * 64 + i * 16 + q * 4 + rr;
            float cs = covb[s];
            float p = 0.f;
#pragma unroll
            for (int j = 0; j < 4; ++j) {
                float att = acc[i][j][rr] + dec_e[j] + cs * wc_e[j];
                p += v_e[j] * fast_tanh(att);
            }
            p += __shfl_xor(p, 1);
            p += __shfl_xor(p, 2);
            p += __shfl_xor(p, 4);
            p += __shfl_xor(p, 8);
            if (c == 0) pp[s] = p;
        }
}

// fallback dec gemm (bf16 Ws, full K, with bias)
__global__ __launch_bounds__(256) void dec_gemm(
    const float* __restrict__ hd, const float* __restrict__ cd,
    const short* __restrict__ Ws, const float* __restrict__ Wsb,
    float* __restrict__ dec_feat)
{
    __shared__ __align__(16) short As[128 * 40];
    __shared__ __align__(16) short Bs[128 * 40];
    const int t = threadIdx.x;
    const int bx = blockIdx.x;
    const int wv = t >> 6, lane = t & 63, q = lane >> 4, c = lane & 15;
    const int wm = wv & 1, wn = wv >> 1;
    const int ar = t >> 1, ah = t & 1;

    const short* bptr = Ws + ((size_t)(bx * 128 + ar)) * 1024 + ah * 16;
    short* awr = &As[ar * 40 + ah * 16];
    short* bwr = &Bs[ar * 40 + ah * 16];

    f32x4 acc[4][4];
#pragma unroll
    for (int i = 0; i < 4; ++i)
#pragma unroll
        for (int j = 0; j < 4; ++j) acc[i][j] = (f32x4){0.f, 0.f, 0.f, 0.f};

    for (int k0 = 0; k0 < 1024; k0 += 32) {
        const int k = k0 + ah * 16;
        const float* src = (k < 512) ? (hd + (size_t)ar * 512 + k)
                                     : (cd + (size_t)ar * 512 + (k - 512));
        const float4* ap = (const float4*)src;
        float4 a0 = ap[0], a1 = ap[1], a2 = ap[2], a3 = ap[3];
        bf16x8 bv0 = *(const bf16x8*)(bptr + k0);
        bf16x8 bv1 = *(const bf16x8*)(bptr + k0 + 8);
        *(bf16x8*)awr = cvt8(a0, a1);
        *(bf16x8*)(awr + 8) = cvt8(a2, a3);
        *(bf16x8*)bwr = bv0;
        *(bf16x8*)(bwr + 8) = bv1;
        __syncthreads();
        bf16x8 af[4], bf[4];
#pragma unroll
        for (int i = 0; i < 4; ++i) af[i] = *(const bf16x8*)&As[(wm * 64 + i * 16 + c) * 40 + q * 8];
#pragma unroll
        for (int j = 0; j < 4; ++j) bf[j] = *(const bf16x8*)&Bs[(wn * 64 + j * 16 + c) * 40 + q * 8];
#pragma unroll
        for (int i = 0; i < 4; ++i)
#pragma unroll
            for (int j = 0; j < 4; ++j)
                acc[i][j] = __builtin_amdgcn_mfma_f32_16x16x32_bf16(af[i], bf[j], acc[i][j], 0, 0, 0);
        __syncthreads();
    }

    const int n0 = bx * 128 + wn * 64;
    float wsb_e[4];
#pragma unroll
    for (int j = 0; j < 4; ++j) wsb_e[j] = Wsb[n0 + j * 16 + c];
#pragma unroll
    for (int i = 0; i < 4; ++i)
#pragma unroll
        for (int rr = 0; rr < 4; ++rr) {
            int bidx = wm * 64 + i * 16 + q * 4 + rr;
#pragma unroll
            for (int j = 0; j < 4; ++j) {
                int e = n0 + j * 16 + c;
                dec_feat[(size_t)bidx * 1024 + e] = acc[i][j][rr] + wsb_e[j];
            }
        }
}

// ---------------- softmax: sum 16 partials, masked softmax + renorm ------------
__global__ __launch_bounds__(512) void softmax_kernel(
    const float* __restrict__ p_part, const float* __restrict__ mask,
    const float* __restrict__ cov, float* __restrict__ aw, float* __restrict__ ncov)
{
    __shared__ float red[8];
    const int b = blockIdx.x, t = threadIdx.x;
    const int w = t >> 6, lane = t & 63;
    const size_t idx = (size_t)b * 512 + t;

    float sc = 0.f;
#pragma unroll
    for (int k = 0; k < 16; ++k) sc += p_part[(size_t)k * 65536 + idx];

    float m = sc;
#pragma unroll
    for (int o = 1; o < 64; o <<= 1) m = fmaxf(m, __shfl_xor(m, o));
    if (lane == 0) red[w] = m;
    __syncthreads();
#pragma unroll
    for (int i = 0; i < 8; ++i) m = fmaxf(m, red[i]);
    __syncthreads();

    float e = __expf(sc - m);
    float s = e;
#pragma unroll
    for (int o = 1; o < 64; o <<= 1) s += __shfl_xor(s, o);
    if (lane == 0) red[w] = s;
    __syncthreads();
    s = 0.f;
#pragma unroll
    for (int i = 0; i < 8; ++i) s += red[i];
    __syncthreads();

    float wv = (e / s) * mask[idx];
    float s2 = wv;
#pragma unroll
    for (int o = 1; o < 64; o <<= 1) s2 += __shfl_xor(s2, o);
    if (lane == 0) red[w] = s2;
    __syncthreads();
    s2 = 0.f;
#pragma unroll
    for (int i = 0; i < 8; ++i) s2 += red[i];

    float awv = wv / s2;
    aw[idx] = awv;
    ncov[idx] = cov[idx] + awv;
}

// ---------------- context: partial-sum (no atomics) + reduce -------------------
__global__ __launch_bounds__(256) void context_part(
    const short* __restrict__ encb, const float* __restrict__ aw, float* __restrict__ cpart)
{
    const int sc = blockIdx.x & 7;     // s-chunk of 64
    const int b  = blockIdx.x >> 3;    // 0..127
    const int t  = threadIdx.x;
    const int dl = t & 127;
    const int si = t >> 7;
    const short* ebase = encb + ((size_t)(b * 512 + sc * 64 + si)) * 1024 + dl * 8;
    const float* awp = aw + (size_t)b * 512 + sc * 64 + si;
    float acc[8];
#pragma unroll
    for (int i = 0; i < 8; ++i) acc[i] = 0.f;
#pragma unroll 16
    for (int s = 0; s < 64; s += 2) {
        float w = awp[s];
        bf16x8 e = *(const bf16x8*)(ebase + (size_t)s * 1024);
#pragma unroll
        for (int i = 0; i < 8; ++i) acc[i] += w * bf2f(e[i]);
    }
    float* cp = cpart + ((size_t)(sc * 2 + si) * 128 + b) * 1024 + dl * 8;
    *(float4*)(cp)     = (float4){acc[0], acc[1], acc[2], acc[3]};
    *(float4*)(cp + 4) = (float4){acc[4], acc[5], acc[6], acc[7]};
}

__global__ __launch_bounds__(256) void ctx_reduce(
    const float* __restrict__ cpart, float* __restrict__ ctx)
{
    int i = blockIdx.x * 256 + threadIdx.x;
    float s = 0.f;
#pragma unroll
    for (int k = 0; k < 16; ++k) s += cpart[(size_t)k * 131072 + i];
    ctx[i] = s;
}

// fp32 fallback context
__global__ __launch_bounds__(256) void context_f32(
    const float* __restrict__ enc, const float* __restrict__ aw, float* __restrict__ ctx)
{
    const int schunk = blockIdx.x;
    const int b = blockIdx.y;
    const int t = threadIdx.x;
    const float* ebase = enc + ((size_t)(b * 512 + schunk * 128)) * 1024 + t * 4;
    const float* awp = aw + (size_t)b * 512 + schunk * 128;
    float ax = 0.f, ay = 0.f, az = 0.f, aww = 0.f;
#pragma unroll 4
    for (int s = 0; s < 128; ++s) {
        float w = awp[s];
        float4 e4 = *(const float4*)(ebase + (size_t)s * 1024);
        ax += w * e4.x; ay += w * e4.y; az += w * e4.z; aww += w * e4.w;
    }
    float* cp = ctx + (size_t)b * 1024 + t * 4;
    atomicAdd(cp + 0, ax);
    atomicAdd(cp + 1, ay);
    atomicAdd(cp + 2, az);
    atomicAdd(cp + 3, aww);
}

extern "C" void kernel_launch(void* const* d_in, const int* in_sizes, int n_in,
                              void* d_out, int out_size, void* d_ws, size_t ws_size,
                              hipStream_t stream) {
    const float* hd   = (const float*)d_in[0];
    const float* cd   = (const float*)d_in[1];
    const float* enc  = (const float*)d_in[2];
    const float* mask = (const float*)d_in[3];
    const float* cov  = (const float*)d_in[4];
    const float* Wh   = (const float*)d_in[5];
    const float* Ws   = (const float*)d_in[6];
    const float* Wsb  = (const float*)d_in[7];
    const float* vw   = (const float*)d_in[8];
    const float* wcw  = (const float*)d_in[9];

    float* out  = (float*)d_out;
    float* ctx  = out;
    float* aw   = out + 131072;
    float* ncov = out + 196608;

    // ws layout (big path): p_part 4MB | dec_part 2MB | Wh_bf 2MB | enc_bf 128MB = 136 MB
    // cpart (8MB) overlays [p_part|dec_part|Wh_bf] — dead by context time.
    char* ws = (char*)d_ws;
    float* p_part   = (float*)ws;
    float* dec_part = (float*)(ws + (4u << 20));
    short* Wh_bf    = (short*)(ws + (6u << 20));
    short* enc_bf   = (short*)(ws + (8u << 20));
    float* cpart    = (float*)ws;
    const size_t need_big = (8ull << 20) + (128ull << 20);

    if (ws_size >= need_big) {
        cvt_all<<<33280, 256, 0, stream>>>(enc, Wh, enc_bf, Wh_bf);
        dec_gemm_sk<<<32, 256, 0, stream>>>(hd, cd, Ws, dec_part);
        attn_score_gemm4<<<4096, 256, 0, stream>>>(enc_bf, Wh_bf, dec_part, Wsb, cov, wcw, vw, p_part);
        softmax_kernel<<<128, 512, 0, stream>>>(p_part, mask, cov, aw, ncov);
        context_part<<<1024, 256, 0, stream>>>(enc_bf, aw, cpart);
        ctx_reduce<<<512, 256, 0, stream>>>(cpart, ctx);
    } else {
        // fallback layout: p_part 4MB | dec_feat 512KB | Wh_bf 2MB | Ws_bf 2MB
        float* dec_feat = (float*)(ws + (4u << 20));
        short* Wh_bf2   = (short*)(ws + (4u << 20) + (512u << 10));
        short* Ws_bf    = (short*)(ws + (6u << 20) + (512u << 10));
        hipMemsetAsync(ctx, 0, 128 * 1024 * sizeof(float), stream);
        cvt_f32_bf16<<<1024, 256, 0, stream>>>(Wh, Wh_bf2, 1024 * 1024);
        cvt_f32_bf16<<<1024, 256, 0, stream>>>(Ws, Ws_bf, 1024 * 1024);
        dec_gemm<<<8, 256, 0, stream>>>(hd, cd, Ws_bf, Wsb, dec_feat);
        attn_score_gemm_fb<<<dim3(8, 512), 256, 0, stream>>>(enc, Wh_bf2, dec_feat, cov, wcw, vw, p_part);
        softmax_kernel<<<128, 512, 0, stream>>>(p_part, mask, cov, aw, ncov);
        context_f32<<<dim3(4, 128), 256, 0, stream>>>(enc, aw, ctx);
    }
}

// Round 5
// 638.007 us; speedup vs baseline: 1.1951x; 1.0251x over previous
//
#include <hip/hip_runtime.h>
#include <hip/hip_bf16.h>
#include <cstdint>
#include <cstddef>

// Problem: B=128, S=512, H=512, D=1024
// Outputs (flat in d_out): context (128*1024) | aw (128*512) | new_coverage (128*512)

typedef __attribute__((ext_vector_type(8))) short bf16x8;
typedef __attribute__((ext_vector_type(4))) float f32x4;

#define GLOBAL_AS(p) ((const __attribute__((address_space(1))) unsigned int*)(p))
#define LDS_AS(p)    ((__attribute__((address_space(3))) unsigned int*)(p))

__device__ __forceinline__ short f2bf(float f) {
    union { float f; uint32_t u; } v; v.f = f;
    uint32_t u = v.u + 0x7fffu + ((v.u >> 16) & 1u);  // RNE
    return (short)(u >> 16);
}

__device__ __forceinline__ float bf2f(short s) {
    union { uint32_t u; float f; } v; v.u = ((uint32_t)(uint16_t)s) << 16;
    return v.f;
}

__device__ __forceinline__ bf16x8 cvt8(float4 a, float4 b) {
    bf16x8 r;
    r[0] = f2bf(a.x); r[1] = f2bf(a.y); r[2] = f2bf(a.z); r[3] = f2bf(a.w);
    r[4] = f2bf(b.x); r[5] = f2bf(b.y); r[6] = f2bf(b.z); r[7] = f2bf(b.w);
    return r;
}

__device__ __forceinline__ float fast_tanh(float x) {
    x = fminf(10.f, fmaxf(-10.f, x));
    float e = __expf(2.f * x);
    return (e - 1.f) / (e + 1.f);
}

// ---------------- fused: fp32->bf16 cvt of [enc|Wh]  +  dec split-K GEMM -------
// blocks [0, 33280): cvt 8 elems/thread. blocks [33280, 33312): dec GEMM.
__global__ __launch_bounds__(256) void cvt_plus_dec(
    const float* __restrict__ enc, const float* __restrict__ Wh,
    short* __restrict__ enc_bf, short* __restrict__ Wh_bf,
    const float* __restrict__ hd, const float* __restrict__ cd,
    const float* __restrict__ Ws, float* __restrict__ dec_part)
{
    __shared__ __align__(16) short As[128 * 40];
    __shared__ __align__(16) short Bs[128 * 40];
    const int t = threadIdx.x;

    if (blockIdx.x < 33280) {
        size_t i = ((size_t)blockIdx.x * 256 + t) * 8;
        const float* src; short* dst; size_t off;
        const size_t NE = 67108864;   // 128*512*1024
        if (i < NE) { src = enc; dst = enc_bf; off = i; }
        else        { src = Wh;  dst = Wh_bf;  off = i - NE; }
        float4 a = *(const float4*)(src + off);
        float4 b = *(const float4*)(src + off + 4);
        *(bf16x8*)(dst + off) = cvt8(a, b);
        return;
    }

    // ---- dec GEMM: M=128, N=1024, K split 4x256 ----
    const int bid = blockIdx.x - 33280;
    const int bx = bid & 7;        // n-tile 0..7
    const int kc = bid >> 3;       // k-chunk 0..3
    const int wv = t >> 6, lane = t & 63, q = lane >> 4, c = lane & 15;
    const int wm = wv & 1, wn = wv >> 1;
    const int ar = t >> 1, ah = t & 1;

    const float* abase = ((kc < 2) ? hd : cd) + (size_t)ar * 512 + (kc & 1) * 256 + ah * 16;
    const float* bbase = Ws + ((size_t)(bx * 128 + ar)) * 1024 + kc * 256 + ah * 16;
    short* awr = &As[ar * 40 + ah * 16];
    short* bwr = &Bs[ar * 40 + ah * 16];

    f32x4 acc[4][4];
#pragma unroll
    for (int i = 0; i < 4; ++i)
#pragma unroll
        for (int j = 0; j < 4; ++j) acc[i][j] = (f32x4){0.f, 0.f, 0.f, 0.f};

    for (int k0 = 0; k0 < 256; k0 += 32) {
        const float4* ap = (const float4*)(abase + k0);
        const float4* bp = (const float4*)(bbase + k0);
        float4 a0 = ap[0], a1 = ap[1], a2 = ap[2], a3 = ap[3];
        float4 b0 = bp[0], b1 = bp[1], b2 = bp[2], b3 = bp[3];
        *(bf16x8*)awr = cvt8(a0, a1);
        *(bf16x8*)(awr + 8) = cvt8(a2, a3);
        *(bf16x8*)bwr = cvt8(b0, b1);
        *(bf16x8*)(bwr + 8) = cvt8(b2, b3);
        __syncthreads();
        bf16x8 af[4], bf[4];
#pragma unroll
        for (int i = 0; i < 4; ++i) af[i] = *(const bf16x8*)&As[(wm * 64 + i * 16 + c) * 40 + q * 8];
#pragma unroll
        for (int j = 0; j < 4; ++j) bf[j] = *(const bf16x8*)&Bs[(wn * 64 + j * 16 + c) * 40 + q * 8];
#pragma unroll
        for (int i = 0; i < 4; ++i)
#pragma unroll
            for (int j = 0; j < 4; ++j)
                acc[i][j] = __builtin_amdgcn_mfma_f32_16x16x32_bf16(af[i], bf[j], acc[i][j], 0, 0, 0);
        __syncthreads();
    }

    const int n0 = bx * 128 + wn * 64;
    float* dp = dec_part + (size_t)kc * 131072;
#pragma unroll
    for (int i = 0; i < 4; ++i)
#pragma unroll
        for (int rr = 0; rr < 4; ++rr) {
            int bidx = wm * 64 + i * 16 + q * 4 + rr;
#pragma unroll
            for (int j = 0; j < 4; ++j)
                dp[(size_t)bidx * 1024 + n0 + j * 16 + c] = acc[i][j][rr];
        }
}

// ---------------- main score GEMM: 256x128 tile, wave=64x128, dbuf -------------
// M=65536, N=1024, K=1024. 2048 blocks. Wave covers full n-tile -> p_part has
// only 8 slices (one per n-tile). LDS reads per wave-iter: 12 x b128 feeding
// 32 MFMA (0.375 reads/MFMA vs 0.5 before).
__global__ __launch_bounds__(256, 2) void attn_score_gemm5(
    const short* __restrict__ encb, const short* __restrict__ Whb,
    const float* __restrict__ dec_part, const float* __restrict__ Wsb,
    const float* __restrict__ cov,
    const float* __restrict__ wc_w, const float* __restrict__ v_w,
    float* __restrict__ p_part)
{
    __shared__ __align__(16) short As[2][256 * 32];  // 32 KB
    __shared__ __align__(16) short Bs[2][128 * 32];  // 16 KB
    const int t = threadIdx.x;
    const int lin = blockIdx.x;
    const int xcd = lin & 7;
    const int kk  = lin >> 3;                  // 0..255
    const int bx  = kk & 7;                    // n-tile (fast within XCD)
    const int my  = xcd * 32 + (kk >> 3);      // m-tile 0..255 (256 rows each)
    const int m0  = my * 256;
    const int b   = my >> 1;
    const int s0  = (my & 1) * 256;

    const int wv = t >> 6, lane = t & 63, q = lane >> 4, c = lane & 15;

    // staging: lane l -> local row (l>>2) within a 16-row group, col-slot (l&3)
    const int srow4 = lane >> 2;               // 0..15
    const int gg = (lane & 3) ^ ((srow4 ^ (srow4 >> 2)) & 3);   // swizzled colgroup

    const short* ag[4];
    int loA[4];
#pragma unroll
    for (int p = 0; p < 4; ++p) {
        int row = p * 64 + wv * 16 + srow4;
        ag[p] = encb + ((size_t)(m0 + row)) * 1024 + gg * 8;
        loA[p] = (p * 64 + wv * 16) * 32;
    }
    const short* bg[2];
    int loB[2];
#pragma unroll
    for (int r = 0; r < 2; ++r) {
        int row = r * 64 + wv * 16 + srow4;
        bg[r] = Whb + ((size_t)(bx * 128 + row)) * 1024 + gg * 8;
        loB[r] = (r * 64 + wv * 16) * 32;
    }

    // fragment-read swizzle (row ≡ c mod 16)
    const int qa = (q ^ ((c ^ (c >> 2)) & 3)) * 8;

    f32x4 acc[4][8];
#pragma unroll
    for (int i = 0; i < 4; ++i)
#pragma unroll
        for (int j = 0; j < 8; ++j) acc[i][j] = (f32x4){0.f, 0.f, 0.f, 0.f};

    // prologue: stage k-tile 0 into buffer 0
#pragma unroll
    for (int p = 0; p < 4; ++p)
        __builtin_amdgcn_global_load_lds(GLOBAL_AS(ag[p]), LDS_AS(&As[0][loA[p]]), 16, 0, 0);
#pragma unroll
    for (int r = 0; r < 2; ++r)
        __builtin_amdgcn_global_load_lds(GLOBAL_AS(bg[r]), LDS_AS(&Bs[0][loB[r]]), 16, 0, 0);
    __syncthreads();

    for (int k0 = 0; k0 < 32; ++k0) {
        const int cur = k0 & 1;
        if (k0 < 31) {
            const int nxt = cur ^ 1;
            const int kb = (k0 + 1) * 32;
#pragma unroll
            for (int p = 0; p < 4; ++p)
                __builtin_amdgcn_global_load_lds(GLOBAL_AS(ag[p] + kb), LDS_AS(&As[nxt][loA[p]]), 16, 0, 0);
#pragma unroll
            for (int r = 0; r < 2; ++r)
                __builtin_amdgcn_global_load_lds(GLOBAL_AS(bg[r] + kb), LDS_AS(&Bs[nxt][loB[r]]), 16, 0, 0);
        }
        bf16x8 af[4], bf[8];
#pragma unroll
        for (int i = 0; i < 4; ++i) af[i] = *(const bf16x8*)&As[cur][(wv * 64 + i * 16 + c) * 32 + qa];
#pragma unroll
        for (int j = 0; j < 8; ++j) bf[j] = *(const bf16x8*)&Bs[cur][(j * 16 + c) * 32 + qa];
#pragma unroll
        for (int i = 0; i < 4; ++i)
#pragma unroll
            for (int j = 0; j < 8; ++j)
                acc[i][j] = __builtin_amdgcn_mfma_f32_16x16x32_bf16(af[i], bf[j], acc[i][j], 0, 0, 0);
        __syncthreads();   // drains next-iter DMA (vmcnt) + cur reads (lgkmcnt)
    }

    // Epilogue: p = sum over this n-tile's 128 e of v[e]*tanh(acc + dec + cov*wc)
    const int n0 = bx * 128;
    float v_e[8], wc_e[8], dec_e[8];
#pragma unroll
    for (int j = 0; j < 8; ++j) {
        int e = n0 + j * 16 + c;
        v_e[j]  = v_w[e];
        wc_e[j] = wc_w[e];
        float d = Wsb[e];
#pragma unroll
        for (int p = 0; p < 4; ++p) d += dec_part[(size_t)p * 131072 + (size_t)b * 1024 + e];
        dec_e[j] = d;
    }
    const float* covb = cov + (size_t)b * 512;
    float* pp = p_part + (size_t)bx * 65536 + (size_t)b * 512;
#pragma unroll
    for (int i = 0; i < 4; ++i)
#pragma unroll
        for (int rr = 0; rr < 4; ++rr) {
            int s = s0 + wv * 64 + i * 16 + q * 4 + rr;
            float cs = covb[s];
            float p = 0.f;
#pragma unroll
            for (int j = 0; j < 8; ++j) {
                float att = acc[i][j][rr] + dec_e[j] + cs * wc_e[j];
                p += v_e[j] * fast_tanh(att);
            }
            p += __shfl_xor(p, 1);
            p += __shfl_xor(p, 2);
            p += __shfl_xor(p, 4);
            p += __shfl_xor(p, 8);
            if (c == 0) pp[s] = p;
        }
}

// ---------------- fallback score GEMM (fp32 A, register cvt, 16 slices) --------
__global__ __launch_bounds__(256) void attn_score_gemm_fb(
    const float* __restrict__ enc, const short* __restrict__ Wh,
    const float* __restrict__ dec_feat, const float* __restrict__ cov,
    const float* __restrict__ wc_w, const float* __restrict__ v_w,
    float* __restrict__ p_part)
{
    __shared__ __align__(16) short As[128 * 40];
    __shared__ __align__(16) short Bs[128 * 40];
    const int t = threadIdx.x;
    const int bx = blockIdx.x;
    const int by = blockIdx.y;
    const int b  = by >> 2;
    const int s0 = (by & 3) * 128;

    const int wv = t >> 6, lane = t & 63, q = lane >> 4, c = lane & 15;
    const int wm = wv & 1, wn = wv >> 1;
    const int ar = t >> 1, ah = t & 1;

    const float* aptr = enc + ((size_t)(by * 128 + ar)) * 1024 + ah * 16;
    const short* bptr = Wh + ((size_t)(bx * 128 + ar)) * 1024 + ah * 16;
    short* awr = &As[ar * 40 + ah * 16];
    short* bwr = &Bs[ar * 40 + ah * 16];

    f32x4 acc[4][4];
#pragma unroll
    for (int i = 0; i < 4; ++i)
#pragma unroll
        for (int j = 0; j < 4; ++j) acc[i][j] = (f32x4){0.f, 0.f, 0.f, 0.f};

    for (int k0 = 0; k0 < 1024; k0 += 32) {
        const float4* ap = (const float4*)(aptr + k0);
        float4 a0 = ap[0], a1 = ap[1], a2 = ap[2], a3 = ap[3];
        bf16x8 bv0 = *(const bf16x8*)(bptr + k0);
        bf16x8 bv1 = *(const bf16x8*)(bptr + k0 + 8);
        *(bf16x8*)awr = cvt8(a0, a1);
        *(bf16x8*)(awr + 8) = cvt8(a2, a3);
        *(bf16x8*)bwr = bv0;
        *(bf16x8*)(bwr + 8) = bv1;
        __syncthreads();
        bf16x8 af[4], bf[4];
#pragma unroll
        for (int i = 0; i < 4; ++i) af[i] = *(const bf16x8*)&As[(wm * 64 + i * 16 + c) * 40 + q * 8];
#pragma unroll
        for (int j = 0; j < 4; ++j) bf[j] = *(const bf16x8*)&Bs[(wn * 64 + j * 16 + c) * 40 + q * 8];
#pragma unroll
        for (int i = 0; i < 4; ++i)
#pragma unroll
            for (int j = 0; j < 4; ++j)
                acc[i][j] = __builtin_amdgcn_mfma_f32_16x16x32_bf16(af[i], bf[j], acc[i][j], 0, 0, 0);
        __syncthreads();
    }

    const int n0 = bx * 128 + wn * 64;
    float v_e[4], wc_e[4], dec_e[4];
#pragma unroll
    for (int j = 0; j < 4; ++j) {
        int e = n0 + j * 16 + c;
        v_e[j]  = v_w[e];
        wc_e[j] = wc_w[e];
        dec_e[j] = dec_feat[(size_t)b * 1024 + e];
    }
    const float* covb = cov + (size_t)b * 512;
    float* pp = p_part + ((size_t)(bx * 2 + wn)) * 65536 + (size_t)b * 512;
#pragma unroll
    for (int i = 0; i < 4; ++i)
#pragma unroll
        for (int rr = 0; rr < 4; ++rr) {
            int s = s0 + wm * 64 + i * 16 + q * 4 + rr;
            float cs = covb[s];
            float p = 0.f;
#pragma unroll
            for (int j = 0; j < 4; ++j) {
                float att = acc[i][j][rr] + dec_e[j] + cs * wc_e[j];
                p += v_e[j] * fast_tanh(att);
            }
            p += __shfl_xor(p, 1);
            p += __shfl_xor(p, 2);
            p += __shfl_xor(p, 4);
            p += __shfl_xor(p, 8);
            if (c == 0) pp[s] = p;
        }
}

// fallback dec gemm (bf16 Ws, full K, with bias)
__global__ __launch_bounds__(256) void dec_gemm(
    const float* __restrict__ hd, const float* __restrict__ cd,
    const short* __restrict__ Ws, const float* __restrict__ Wsb,
    float* __restrict__ dec_feat)
{
    __shared__ __align__(16) short As[128 * 40];
    __shared__ __align__(16) short Bs[128 * 40];
    const int t = threadIdx.x;
    const int bx = blockIdx.x;
    const int wv = t >> 6, lane = t & 63, q = lane >> 4, c = lane & 15;
    const int wm = wv & 1, wn = wv >> 1;
    const int ar = t >> 1, ah = t & 1;

    const short* bptr = Ws + ((size_t)(bx * 128 + ar)) * 1024 + ah * 16;
    short* awr = &As[ar * 40 + ah * 16];
    short* bwr = &Bs[ar * 40 + ah * 16];

    f32x4 acc[4][4];
#pragma unroll
    for (int i = 0; i < 4; ++i)
#pragma unroll
        for (int j = 0; j < 4; ++j) acc[i][j] = (f32x4){0.f, 0.f, 0.f, 0.f};

    for (int k0 = 0; k0 < 1024; k0 += 32) {
        const int k = k0 + ah * 16;
        const float* src = (k < 512) ? (hd + (size_t)ar * 512 + k)
                                     : (cd + (size_t)ar * 512 + (k - 512));
        const float4* ap = (const float4*)src;
        float4 a0 = ap[0], a1 = ap[1], a2 = ap[2], a3 = ap[3];
        bf16x8 bv0 = *(const bf16x8*)(bptr + k0);
        bf16x8 bv1 = *(const bf16x8*)(bptr + k0 + 8);
        *(bf16x8*)awr = cvt8(a0, a1);
        *(bf16x8*)(awr + 8) = cvt8(a2, a3);
        *(bf16x8*)bwr = bv0;
        *(bf16x8*)(bwr + 8) = bv1;
        __syncthreads();
        bf16x8 af[4], bf[4];
#pragma unroll
        for (int i = 0; i < 4; ++i) af[i] = *(const bf16x8*)&As[(wm * 64 + i * 16 + c) * 40 + q * 8];
#pragma unroll
        for (int j = 0; j < 4; ++j) bf[j] = *(const bf16x8*)&Bs[(wn * 64 + j * 16 + c) * 40 + q * 8];
#pragma unroll
        for (int i = 0; i < 4; ++i)
#pragma unroll
            for (int j = 0; j < 4; ++j)
                acc[i][j] = __builtin_amdgcn_mfma_f32_16x16x32_bf16(af[i], bf[j], acc[i][j], 0, 0, 0);
        __syncthreads();
    }

    const int n0 = bx * 128 + wn * 64;
    float wsb_e[4];
#pragma unroll
    for (int j = 0; j < 4; ++j) wsb_e[j] = Wsb[n0 + j * 16 + c];
#pragma unroll
    for (int i = 0; i < 4; ++i)
#pragma unroll
        for (int rr = 0; rr < 4; ++rr) {
            int bidx = wm * 64 + i * 16 + q * 4 + rr;
#pragma unroll
            for (int j = 0; j < 4; ++j) {
                int e = n0 + j * 16 + c;
                dec_feat[(size_t)bidx * 1024 + e] = acc[i][j][rr] + wsb_e[j];
            }
        }
}

// ---------------- softmax: sum ns partials, masked softmax + renorm ------------
__global__ __launch_bounds__(512) void softmax_kernel(
    const float* __restrict__ p_part, int ns, const float* __restrict__ mask,
    const float* __restrict__ cov, float* __restrict__ aw, float* __restrict__ ncov)
{
    __shared__ float red[8];
    const int b = blockIdx.x, t = threadIdx.x;
    const int w = t >> 6, lane = t & 63;
    const size_t idx = (size_t)b * 512 + t;

    float sc = 0.f;
    for (int k = 0; k < ns; ++k) sc += p_part[(size_t)k * 65536 + idx];

    float m = sc;
#pragma unroll
    for (int o = 1; o < 64; o <<= 1) m = fmaxf(m, __shfl_xor(m, o));
    if (lane == 0) red[w] = m;
    __syncthreads();
#pragma unroll
    for (int i = 0; i < 8; ++i) m = fmaxf(m, red[i]);
    __syncthreads();

    float e = __expf(sc - m);
    float s = e;
#pragma unroll
    for (int o = 1; o < 64; o <<= 1) s += __shfl_xor(s, o);
    if (lane == 0) red[w] = s;
    __syncthreads();
    s = 0.f;
#pragma unroll
    for (int i = 0; i < 8; ++i) s += red[i];
    __syncthreads();

    float wv = (e / s) * mask[idx];
    float s2 = wv;
#pragma unroll
    for (int o = 1; o < 64; o <<= 1) s2 += __shfl_xor(s2, o);
    if (lane == 0) red[w] = s2;
    __syncthreads();
    s2 = 0.f;
#pragma unroll
    for (int i = 0; i < 8; ++i) s2 += red[i];

    float awv = wv / s2;
    aw[idx] = awv;
    ncov[idx] = cov[idx] + awv;
}

// ---------------- context: partial-sum (no atomics) + reduce -------------------
__global__ __launch_bounds__(256) void context_part(
    const short* __restrict__ encb, const float* __restrict__ aw, float* __restrict__ cpart)
{
    const int sc = blockIdx.x & 7;     // s-chunk of 64
    const int b  = blockIdx.x >> 3;    // 0..127
    const int t  = threadIdx.x;
    const int dl = t & 127;
    const int si = t >> 7;
    const short* ebase = encb + ((size_t)(b * 512 + sc * 64 + si)) * 1024 + dl * 8;
    const float* awp = aw + (size_t)b * 512 + sc * 64 + si;
    float acc[8];
#pragma unroll
    for (int i = 0; i < 8; ++i) acc[i] = 0.f;
#pragma unroll 16
    for (int s = 0; s < 64; s += 2) {
        float w = awp[s];
        bf16x8 e = *(const bf16x8*)(ebase + (size_t)s * 1024);
#pragma unroll
        for (int i = 0; i < 8; ++i) acc[i] += w * bf2f(e[i]);
    }
    float* cp = cpart + ((size_t)(sc * 2 + si) * 128 + b) * 1024 + dl * 8;
    *(float4*)(cp)     = (float4){acc[0], acc[1], acc[2], acc[3]};
    *(float4*)(cp + 4) = (float4){acc[4], acc[5], acc[6], acc[7]};
}

__global__ __launch_bounds__(256) void ctx_reduce(
    const float* __restrict__ cpart, float* __restrict__ ctx)
{
    int i = blockIdx.x * 256 + threadIdx.x;
    float s = 0.f;
#pragma unroll
    for (int k = 0; k < 16; ++k) s += cpart[(size_t)k * 131072 + i];
    ctx[i] = s;
}

// fp32 fallback context
__global__ __launch_bounds__(256) void context_f32(
    const float* __restrict__ enc, const float* __restrict__ aw, float* __restrict__ ctx)
{
    const int schunk = blockIdx.x;
    const int b = blockIdx.y;
    const int t = threadIdx.x;
    const float* ebase = enc + ((size_t)(b * 512 + schunk * 128)) * 1024 + t * 4;
    const float* awp = aw + (size_t)b * 512 + schunk * 128;
    float ax = 0.f, ay = 0.f, az = 0.f, aww = 0.f;
#pragma unroll 4
    for (int s = 0; s < 128; ++s) {
        float w = awp[s];
        float4 e4 = *(const float4*)(ebase + (size_t)s * 1024);
        ax += w * e4.x; ay += w * e4.y; az += w * e4.z; aww += w * e4.w;
    }
    float* cp = ctx + (size_t)b * 1024 + t * 4;
    atomicAdd(cp + 0, ax);
    atomicAdd(cp + 1, ay);
    atomicAdd(cp + 2, az);
    atomicAdd(cp + 3, aww);
}

// small cvt for fallback path (weights only)
__global__ void cvt_f32_bf16(const float* __restrict__ src, short* __restrict__ dst, int n) {
    int i = (blockIdx.x * 256 + threadIdx.x) * 4;
    if (i < n) {
        float4 f = *(const float4*)(src + i);
        short4 o;
        o.x = f2bf(f.x); o.y = f2bf(f.y); o.z = f2bf(f.z); o.w = f2bf(f.w);
        *(short4*)(dst + i) = o;
    }
}

extern "C" void kernel_launch(void* const* d_in, const int* in_sizes, int n_in,
                              void* d_out, int out_size, void* d_ws, size_t ws_size,
                              hipStream_t stream) {
    const float* hd   = (const float*)d_in[0];
    const float* cd   = (const float*)d_in[1];
    const float* enc  = (const float*)d_in[2];
    const float* mask = (const float*)d_in[3];
    const float* cov  = (const float*)d_in[4];
    const float* Wh   = (const float*)d_in[5];
    const float* Ws   = (const float*)d_in[6];
    const float* Wsb  = (const float*)d_in[7];
    const float* vw   = (const float*)d_in[8];
    const float* wcw  = (const float*)d_in[9];

    float* out  = (float*)d_out;
    float* ctx  = out;
    float* aw   = out + 131072;
    float* ncov = out + 196608;

    // ws layout (big path): p_part 2MB | dec_part 2MB | Wh_bf 2MB | pad 2MB | enc_bf 128MB
    // cpart (8MB) overlays [0..8MB) — all dead by context time.
    char* ws = (char*)d_ws;
    float* p_part   = (float*)ws;
    float* dec_part = (float*)(ws + (2u << 20));
    short* Wh_bf    = (short*)(ws + (4u << 20));
    short* enc_bf   = (short*)(ws + (8u << 20));
    float* cpart    = (float*)ws;
    const size_t need_big = (8ull << 20) + (128ull << 20);

    if (ws_size >= need_big) {
        cvt_plus_dec<<<33312, 256, 0, stream>>>(enc, Wh, enc_bf, Wh_bf, hd, cd, Ws, dec_part);
        attn_score_gemm5<<<2048, 256, 0, stream>>>(enc_bf, Wh_bf, dec_part, Wsb, cov, wcw, vw, p_part);
        softmax_kernel<<<128, 512, 0, stream>>>(p_part, 8, mask, cov, aw, ncov);
        context_part<<<1024, 256, 0, stream>>>(enc_bf, aw, cpart);
        ctx_reduce<<<512, 256, 0, stream>>>(cpart, ctx);
    } else {
        // fallback layout: p_part 4MB | dec_feat 512KB | Wh_bf 2MB | Ws_bf 2MB
        float* p_part16 = (float*)ws;
        float* dec_feat = (float*)(ws + (4u << 20));
        short* Wh_bf2   = (short*)(ws + (4u << 20) + (512u << 10));
        short* Ws_bf    = (short*)(ws + (6u << 20) + (512u << 10));
        hipMemsetAsync(ctx, 0, 128 * 1024 * sizeof(float), stream);
        cvt_f32_bf16<<<1024, 256, 0, stream>>>(Wh, Wh_bf2, 1024 * 1024);
        cvt_f32_bf16<<<1024, 256, 0, stream>>>(Ws, Ws_bf, 1024 * 1024);
        dec_gemm<<<8, 256, 0, stream>>>(hd, cd, Ws_bf, Wsb, dec_feat);
        attn_score_gemm_fb<<<dim3(8, 512), 256, 0, stream>>>(enc, Wh_bf2, dec_feat, cov, wcw, vw, p_part16);
        softmax_kernel<<<128, 512, 0, stream>>>(p_part16, 16, mask, cov, aw, ncov);
        context_f32<<<dim3(4, 128), 256, 0, stream>>>(enc, aw, ctx);
    }
}